// Round 1
// baseline (844.815 us; speedup 1.0000x reference)
//
#include <hip/hip_runtime.h>

// Problem constants (fixed by the reference)
constexpr int NC = 100000;   // cards
constexpr int NM = 20000;    // merchants
constexpr int NE = 400000;   // edges per edge-type

// d_out layout (floats), concat of (xc2, xm2, pred_c, pred_m, risk_c, risk_m)
constexpr int OFF_XM2 = NC * 128;            // 12,800,000
constexpr int OFF_PC  = OFF_XM2 + NM * 128;  // 15,360,000
constexpr int OFF_PM  = OFF_PC + NC * 2;     // 15,560,000
constexpr int OFF_RC  = OFF_PM + NM * 2;     // 15,600,000
constexpr int OFF_RM  = OFF_RC + NC;         // 15,700,000

// ---------------------------------------------------------------- utilities
__global__ void k_zero(int* a, int na, int* b, int nb) {
  int i = blockIdx.x * blockDim.x + threadIdx.x;
  int tot = na + nb;
  int stride = gridDim.x * blockDim.x;
  for (; i < tot; i += stride) {
    if (i < na) a[i] = 0; else b[i - na] = 0;
  }
}

// v[k*4+h] = sum_c Wdst[k*128 + h*32 + c] * adst[h*32 + c]   (a_d GEMV vector)
__global__ void k_prepv(const float* W0, const float* a0, float* v0,
                        const float* W1, const float* a1, float* v1,
                        const float* W2, const float* a2, float* v2,
                        const float* W3, const float* a3, float* v3) {
  const float* W; const float* a; float* v; int K;
  switch (blockIdx.x) {
    case 0:  W = W0; a = a0; v = v0; K = 64;  break;
    case 1:  W = W1; a = a1; v = v1; K = 64;  break;
    case 2:  W = W2; a = a2; v = v2; K = 128; break;
    default: W = W3; a = a3; v = v3; K = 128; break;
  }
  for (int idx = threadIdx.x; idx < K * 4; idx += blockDim.x) {
    int k = idx >> 2, h = idx & 3;
    float s = 0.f;
    for (int c = 0; c < 32; ++c) s += W[k * 128 + h * 32 + c] * a[h * 32 + c];
    v[idx] = s;
  }
}

// Concatenate cls_W1 || risk_W1 into [128 x 128] (and biases) per node type
__global__ void k_prepw(const float* c1, const float* cb1,
                        const float* m1, const float* mb1,
                        const float* r1, const float* rb1,
                        float* WcatC, float* bC, float* WcatM, float* bM) {
  int i = blockIdx.x * blockDim.x + threadIdx.x;
  if (i < 128 * 128) {
    int k = i >> 7, col = i & 127;
    WcatC[i] = (col < 64) ? c1[k * 64 + col] : r1[k * 64 + (col - 64)];
    WcatM[i] = (col < 64) ? m1[k * 64 + col] : r1[k * 64 + (col - 64)];
  }
  if (i < 128) {
    bC[i] = (i < 64) ? cb1[i] : rb1[i - 64];
    bM[i] = (i < 64) ? mb1[i] : rb1[i - 64];
  }
}

// ---------------------------------------------------------------- CSR build
__global__ void k_hist(const int* cm_dst, const int* mc_dst, int* cnt_cm, int* cnt_mc) {
  int i = blockIdx.x * blockDim.x + threadIdx.x;
  int stride = gridDim.x * blockDim.x;
  for (; i < NE; i += stride) {
    atomicAdd(&cnt_cm[cm_dst[i]], 1);
    atomicAdd(&cnt_mc[mc_dst[i]], 1);
  }
}

// 1024-element chunks: local exclusive scan -> offs, chunk total -> parts
// parts[0..19] = cm chunks, parts[20..117] = mc chunks
__global__ void __launch_bounds__(256) k_scan1(const int* cnt_cm, const int* cnt_mc,
                                               int* offs_cm, int* offs_mc, int* parts) {
  int b = blockIdx.x;
  const int* cnt; int* offs; int n, chunk;
  if (b < 20) { cnt = cnt_cm; offs = offs_cm; n = NM; chunk = b; }
  else        { cnt = cnt_mc; offs = offs_mc; n = NC; chunk = b - 20; }
  int t = threadIdx.x;
  int base = chunk * 1024;
  int v[4]; int tsum = 0;
  #pragma unroll
  for (int j = 0; j < 4; ++j) {
    int idx = base + t * 4 + j;
    v[j] = (idx < n) ? cnt[idx] : 0;
    tsum += v[j];
  }
  __shared__ int sd[256];
  sd[t] = tsum; __syncthreads();
  for (int off = 1; off < 256; off <<= 1) {
    int x = (t >= off) ? sd[t - off] : 0;
    __syncthreads();
    sd[t] += x;
    __syncthreads();
  }
  int excl = sd[t] - tsum;
  int r = excl;
  #pragma unroll
  for (int j = 0; j < 4; ++j) {
    int idx = base + t * 4 + j;
    if (idx < n) offs[idx] = r;
    r += v[j];
  }
  if (t == 0) parts[b] = sd[255];
}

__global__ void __launch_bounds__(256) k_scan2(int* parts) {
  int b = blockIdx.x;
  int base = (b == 0) ? 0 : 20;
  int n = (b == 0) ? 20 : 98;
  int t = threadIdx.x;
  __shared__ int sd[128];
  int v = 0;
  if (t < 128) { v = (t < n) ? parts[base + t] : 0; sd[t] = v; }
  __syncthreads();
  for (int off = 1; off < 128; off <<= 1) {
    int x = 0;
    if (t < 128 && t >= off) x = sd[t - off];
    __syncthreads();
    if (t < 128) sd[t] += x;
    __syncthreads();
  }
  if (t < 128 && t < n) parts[base + t] = sd[t] - v;
}

__global__ void k_scan3(int* offs_cm, int* offs_mc, int* cur_cm, int* cur_mc, const int* parts) {
  int i = blockIdx.x * blockDim.x + threadIdx.x;
  if (i < NM) {
    int val = offs_cm[i] + parts[i >> 10];
    offs_cm[i] = val; cur_cm[i] = val;
  } else if (i < NM + NC) {
    int j = i - NM;
    int val = offs_mc[j] + parts[20 + (j >> 10)];
    offs_mc[j] = val; cur_mc[j] = val;
  }
  if (i == 0) { offs_cm[NM] = NE; offs_mc[NC] = NE; }
}

__global__ void k_scatter(const int* cm_src, const int* cm_dst,
                          const int* mc_src, const int* mc_dst,
                          int* cur_cm, int* cur_mc, int* csr_cm, int* csr_mc) {
  int i = blockIdx.x * blockDim.x + threadIdx.x;
  int stride = gridDim.x * blockDim.x;
  for (; i < NE; i += stride) {
    int p = atomicAdd(&cur_cm[cm_dst[i]], 1);
    csr_cm[p] = cm_src[i];
    int q = atomicAdd(&cur_mc[mc_dst[i]], 1);
    csr_mc[q] = mc_src[i];
  }
}

// ---------------------------------------------------------------- GEMM
// 64-row x 128-col tile per 256-thread block.
// EPI=0: hs = x@W; epilogue computes a_s (asrc reduce) and a_d (x@v GEMV).
// EPI=1: h  = relu(w_row * (x@W) + bias); also writes outx = x * w_row
//        where w_row = wnum[row] / den[0].
template<int K, int EPI>
__global__ void __launch_bounds__(256) k_gemm(
    const float* __restrict__ xA, const float* __restrict__ WA,
    const float* __restrict__ asrcA, const float* __restrict__ vA,
    float* __restrict__ hsA, float* __restrict__ asOutA, float* __restrict__ adOutA,
    const float* __restrict__ biasA, const float* __restrict__ wnumA,
    const float* __restrict__ denA, float* __restrict__ outxA, int MA, int gridA,
    const float* __restrict__ xB, const float* __restrict__ WB,
    const float* __restrict__ asrcB, const float* __restrict__ vB,
    float* __restrict__ hsB, float* __restrict__ asOutB, float* __restrict__ adOutB,
    const float* __restrict__ biasB, const float* __restrict__ wnumB,
    const float* __restrict__ denB, float* __restrict__ outxB, int MB) {
  constexpr int P = K + 4;         // padded LDS pitch (keeps 16B alignment, breaks bank stride)
  constexpr int F4 = K / 4;
  __shared__ float xs[64 * P];
  const float *x, *W, *asrc, *v, *bias, *wnum, *den;
  float *hs, *asO, *adO, *outx;
  int M, blk;
  if ((int)blockIdx.x < gridA) {
    x = xA; W = WA; asrc = asrcA; v = vA; hs = hsA; asO = asOutA; adO = adOutA;
    bias = biasA; wnum = wnumA; den = denA; outx = outxA; M = MA; blk = (int)blockIdx.x;
  } else {
    x = xB; W = WB; asrc = asrcB; v = vB; hs = hsB; asO = asOutB; adO = adOutB;
    bias = biasB; wnum = wnumB; den = denB; outx = outxB; M = MB; blk = (int)blockIdx.x - gridA;
  }
  const int row0 = blk * 64;
  const int t = (int)threadIdx.x;
  // stage x tile (64 x K) into LDS, float4 loads
  const float4* x4 = reinterpret_cast<const float4*>(x);
  #pragma unroll
  for (int ii = 0; ii < (64 * F4) / 256; ++ii) {
    int idx = t + ii * 256;
    int r = idx / F4, f = idx % F4;
    int gr = row0 + r;
    float4 val = {0.f, 0.f, 0.f, 0.f};
    if (gr < M) val = x4[gr * F4 + f];
    *reinterpret_cast<float4*>(&xs[r * P + f * 4]) = val;
  }
  __syncthreads();
  const int tx = t & 31, ty = t >> 5;     // tx: col group (4 cols), ty: row group (8 rows)
  float4 acc[8];
  #pragma unroll
  for (int r = 0; r < 8; ++r) acc[r] = {0.f, 0.f, 0.f, 0.f};
  const float4* W4 = reinterpret_cast<const float4*>(W);
  for (int kk = 0; kk < K; kk += 4) {
    float4 w0 = W4[(kk + 0) * 32 + tx];
    float4 w1 = W4[(kk + 1) * 32 + tx];
    float4 w2 = W4[(kk + 2) * 32 + tx];
    float4 w3 = W4[(kk + 3) * 32 + tx];
    #pragma unroll
    for (int r = 0; r < 8; ++r) {
      float4 xv = *reinterpret_cast<const float4*>(&xs[(ty * 8 + r) * P + kk]);
      acc[r].x += xv.x * w0.x + xv.y * w1.x + xv.z * w2.x + xv.w * w3.x;
      acc[r].y += xv.x * w0.y + xv.y * w1.y + xv.z * w2.y + xv.w * w3.y;
      acc[r].z += xv.x * w0.z + xv.y * w1.z + xv.z * w2.z + xv.w * w3.z;
      acc[r].w += xv.x * w0.w + xv.y * w1.w + xv.z * w2.w + xv.w * w3.w;
    }
  }
  if constexpr (EPI == 0) {
    // store hs
    #pragma unroll
    for (int r = 0; r < 8; ++r) {
      int gr = row0 + ty * 8 + r;
      if (gr < M) *reinterpret_cast<float4*>(&hs[gr * 128 + tx * 4]) = acc[r];
    }
    // epilogue: a_s (reduce acc with asrc) and a_d (GEMV with v) per head
    const int h = tx >> 3, sl = tx & 7;
    float asv[4];
    #pragma unroll
    for (int j = 0; j < 4; ++j) asv[j] = asrc[h * 32 + sl * 4 + j];
    constexpr int SL = K / 8;
    #pragma unroll
    for (int r = 0; r < 8; ++r) {
      int row = ty * 8 + r;
      float p = acc[r].x * asv[0] + acc[r].y * asv[1] + acc[r].z * asv[2] + acc[r].w * asv[3];
      float q = 0.f;
      #pragma unroll
      for (int k2 = 0; k2 < SL; ++k2) {
        int k = sl * SL + k2;
        q += xs[row * P + k] * v[k * 4 + h];
      }
      #pragma unroll
      for (int m = 1; m < 8; m <<= 1) { p += __shfl_xor(p, m); q += __shfl_xor(q, m); }
      int gr = row0 + row;
      if (sl == 0 && gr < M) { asO[gr * 4 + h] = p; adO[gr * 4 + h] = q; }
    }
  } else {
    const float invden = 1.0f / den[0];
    const float4 b4 = *reinterpret_cast<const float4*>(&bias[tx * 4]);
    #pragma unroll
    for (int r = 0; r < 8; ++r) {
      int gr = row0 + ty * 8 + r;
      if (gr < M) {
        float w = wnum[gr] * invden;
        float4 o;
        o.x = fmaxf(acc[r].x * w + b4.x, 0.f);
        o.y = fmaxf(acc[r].y * w + b4.y, 0.f);
        o.z = fmaxf(acc[r].z * w + b4.z, 0.f);
        o.w = fmaxf(acc[r].w * w + b4.w, 0.f);
        *reinterpret_cast<float4*>(&hs[gr * 128 + tx * 4]) = o;
      }
    }
    // also emit the reweighted node features (xc2/xm2 outputs) from the LDS tile
    #pragma unroll
    for (int ii = 0; ii < 8; ++ii) {          // 64 rows * 32 float4 = 2048 / 256
      int idx = t + ii * 256;
      int r = idx >> 5, f = idx & 31;
      int gr = row0 + r;
      if (gr < M) {
        float w = wnum[gr] * invden;
        float4 xv = *reinterpret_cast<const float4*>(&xs[r * P + f * 4]);
        xv.x *= w; xv.y *= w; xv.z *= w; xv.w *= w;
        *reinterpret_cast<float4*>(&outx[gr * 128 + f * 4]) = xv;
      }
    }
  }
}

// ---------------------------------------------------------------- aggregation
// One 128-thread block per destination node. thread t: head h = t>>5, channel t&31.
// Pass 1/2: per-head max & exp-sum over the segment (32 lanes/head).
// Pass 3: all threads accumulate hs[src]*exp(e-m), divide by den once.
__global__ void __launch_bounds__(128) k_agg(
    const int* __restrict__ offsA, const int* __restrict__ csrA,
    const float* __restrict__ asA, const float* __restrict__ adA,
    const float* __restrict__ hsA, const float* __restrict__ biasA,
    float* __restrict__ outA, int ndstA,
    const int* __restrict__ offsB, const int* __restrict__ csrB,
    const float* __restrict__ asB, const float* __restrict__ adB,
    const float* __restrict__ hsB, const float* __restrict__ biasB,
    float* __restrict__ outB) {
  const int* offs; const int* csr; const float* as_; const float* ad;
  const float* hsp; const float* bias; float* out; int d;
  if ((int)blockIdx.x < ndstA) {
    offs = offsA; csr = csrA; as_ = asA; ad = adA; hsp = hsA; bias = biasA; out = outA;
    d = (int)blockIdx.x;
  } else {
    offs = offsB; csr = csrB; as_ = asB; ad = adB; hsp = hsB; bias = biasB; out = outB;
    d = (int)blockIdx.x - ndstA;
  }
  const int t = (int)threadIdx.x, h = t >> 5, l = t & 31;
  const int beg = offs[d], end = offs[d + 1];
  const int deg = end - beg;
  __shared__ float sm[4], sden[4];
  const float adv = ad[d * 4 + h];
  float mx = -1e30f;
  for (int i = l; i < deg; i += 32) {
    int s = csr[beg + i];
    float e = as_[s * 4 + h] + adv;
    e = (e > 0.f) ? e : 0.2f * e;
    mx = fmaxf(mx, e);
  }
  #pragma unroll
  for (int m = 1; m < 32; m <<= 1) mx = fmaxf(mx, __shfl_xor(mx, m, 32));
  float sum = 0.f;
  for (int i = l; i < deg; i += 32) {
    int s = csr[beg + i];
    float e = as_[s * 4 + h] + adv;
    e = (e > 0.f) ? e : 0.2f * e;
    sum += __expf(e - mx);
  }
  #pragma unroll
  for (int m = 1; m < 32; m <<= 1) sum += __shfl_xor(sum, m, 32);
  if (l == 0) { sm[h] = mx; sden[h] = sum; }
  __syncthreads();
  const float mh = sm[h];
  const float invden = (deg > 0) ? 1.f / sden[h] : 0.f;
  float acc = 0.f;
  for (int i = 0; i < deg; ++i) {
    int s = csr[beg + i];
    float e = as_[s * 4 + h] + adv;
    e = (e > 0.f) ? e : 0.2f * e;
    float w = __expf(e - mh);
    acc += hsp[s * 128 + t] * w;
  }
  out[d * 128 + t] = acc * invden + bias[t];
}

// ---------------------------------------------------------------- global softmax + heads
__global__ void __launch_bounds__(256) k_logits(
    const float* __restrict__ xc2, const float* __restrict__ xm2,
    const float* __restrict__ attwc, const float* __restrict__ attbc,
    const float* __restrict__ attwm, const float* __restrict__ attbm,
    float* __restrict__ logc, float* __restrict__ logm,
    float* __restrict__ pmaxc, float* __restrict__ pmaxm) {
  const int NBC = NC / 4;
  bool card = (int)blockIdx.x < NBC;
  int wave = threadIdx.x >> 6, lane = threadIdx.x & 63;
  int n = card ? ((int)blockIdx.x * 4 + wave) : (((int)blockIdx.x - NBC) * 4 + wave);
  const float* x2 = card ? xc2 : xm2;
  const float* aw = card ? attwc : attwm;
  float b = card ? attbc[0] : attbm[0];
  float* logv = card ? logc : logm;
  float s = x2[n * 128 + lane] * aw[lane] + x2[n * 128 + 64 + lane] * aw[64 + lane];
  #pragma unroll
  for (int m = 1; m < 64; m <<= 1) s += __shfl_xor(s, m);
  __shared__ float sl_[4];
  float logit = s + b;
  if (lane == 0) { logv[n] = logit; sl_[wave] = logit; }
  __syncthreads();
  if (threadIdx.x == 0) {
    float mx = fmaxf(fmaxf(sl_[0], sl_[1]), fmaxf(sl_[2], sl_[3]));
    if (card) pmaxc[blockIdx.x] = mx; else pmaxm[blockIdx.x - NBC] = mx;
  }
}

__global__ void __launch_bounds__(1024) k_stats(const float* pmaxc, const float* pmaxm, float* stats) {
  const float* src = (blockIdx.x == 0) ? pmaxc : pmaxm;
  int n = (blockIdx.x == 0) ? NC / 4 : NM / 4;
  float m = -1e30f;
  for (int i = threadIdx.x; i < n; i += 1024) m = fmaxf(m, src[i]);
  __shared__ float sd[1024];
  sd[threadIdx.x] = m; __syncthreads();
  for (int off = 512; off > 0; off >>= 1) {
    if ((int)threadIdx.x < off) sd[threadIdx.x] = fmaxf(sd[threadIdx.x], sd[threadIdx.x + off]);
    __syncthreads();
  }
  if (threadIdx.x == 0) stats[blockIdx.x] = sd[0];
}

__global__ void __launch_bounds__(256) k_expsum(float* logc, float* logm, float* stats) {
  bool card = (int)blockIdx.x < 256;
  float* logv = card ? logc : logm;
  int n = card ? NC : NM;
  float mx = card ? stats[0] : stats[1];
  int b0 = card ? (int)blockIdx.x : (int)blockIdx.x - 256;
  int nb = card ? 256 : 64;
  float local = 0.f;
  for (int i = b0 * 256 + (int)threadIdx.x; i < n; i += nb * 256) {
    float e = __expf(logv[i] - mx);
    logv[i] = e;        // store numerator for later
    local += e;
  }
  __shared__ float sd[256];
  sd[threadIdx.x] = local; __syncthreads();
  for (int off = 128; off > 0; off >>= 1) {
    if ((int)threadIdx.x < off) sd[threadIdx.x] += sd[threadIdx.x + off];
    __syncthreads();
  }
  if (threadIdx.x == 0) atomicAdd(card ? &stats[2] : &stats[3], sd[0]);
}

__global__ void __launch_bounds__(256) k_heads(
    const float* __restrict__ hC, const float* __restrict__ hM,
    const float* __restrict__ w2c, const float* __restrict__ b2c,
    const float* __restrict__ w2m, const float* __restrict__ b2m,
    const float* __restrict__ w2r, const float* __restrict__ b2r,
    float* __restrict__ out) {
  const int NBC = NC / 4;
  bool card = (int)blockIdx.x < NBC;
  int wave = threadIdx.x >> 6, lane = threadIdx.x & 63;
  int n = card ? ((int)blockIdx.x * 4 + wave) : (((int)blockIdx.x - NBC) * 4 + wave);
  const float* h = card ? hC : hM;
  const float* W2 = card ? w2c : w2m;
  const float* B2 = card ? b2c : b2m;
  float hc = h[n * 128 + lane];        // cls hidden (already relu'd)
  float hr = h[n * 128 + 64 + lane];   // risk hidden
  float p0 = hc * W2[lane * 2 + 0];
  float p1 = hc * W2[lane * 2 + 1];
  float rr = hr * w2r[lane];
  #pragma unroll
  for (int m = 1; m < 64; m <<= 1) {
    p0 += __shfl_xor(p0, m);
    p1 += __shfl_xor(p1, m);
    rr += __shfl_xor(rr, m);
  }
  if (lane == 0) {
    float* pout = out + (card ? OFF_PC : OFF_PM);
    float* rout = out + (card ? OFF_RC : OFF_RM);
    pout[n * 2 + 0] = p0 + B2[0];
    pout[n * 2 + 1] = p1 + B2[1];
    float z = rr + b2r[0];
    rout[n] = 1.f / (1.f + __expf(-z));
  }
}

// ---------------------------------------------------------------- launch
extern "C" void kernel_launch(void* const* d_in, const int* in_sizes, int n_in,
                              void* d_out, int out_size, void* d_ws, size_t ws_size,
                              hipStream_t stream) {
  (void)in_sizes; (void)n_in; (void)out_size; (void)ws_size;
  const float* x_card    = (const float*)d_in[0];
  const float* x_mer     = (const float*)d_in[1];
  const float* l0cm_Wsrc = (const float*)d_in[2];
  const float* l0cm_Wdst = (const float*)d_in[3];
  const float* l0cm_asrc = (const float*)d_in[4];
  const float* l0cm_adst = (const float*)d_in[5];
  const float* l0cm_b    = (const float*)d_in[6];
  const float* l0mc_Wsrc = (const float*)d_in[7];
  const float* l0mc_Wdst = (const float*)d_in[8];
  const float* l0mc_asrc = (const float*)d_in[9];
  const float* l0mc_adst = (const float*)d_in[10];
  const float* l0mc_b    = (const float*)d_in[11];
  const float* l1cm_Wsrc = (const float*)d_in[12];
  const float* l1cm_Wdst = (const float*)d_in[13];
  const float* l1cm_asrc = (const float*)d_in[14];
  const float* l1cm_adst = (const float*)d_in[15];
  const float* l1cm_b    = (const float*)d_in[16];
  const float* l1mc_Wsrc = (const float*)d_in[17];
  const float* l1mc_Wdst = (const float*)d_in[18];
  const float* l1mc_asrc = (const float*)d_in[19];
  const float* l1mc_adst = (const float*)d_in[20];
  const float* l1mc_b    = (const float*)d_in[21];
  const float* attw_c    = (const float*)d_in[22];
  const float* attb_c    = (const float*)d_in[23];
  const float* attw_m    = (const float*)d_in[24];
  const float* attb_m    = (const float*)d_in[25];
  const float* clsc_W1   = (const float*)d_in[26];
  const float* clsc_b1   = (const float*)d_in[27];
  const float* clsc_W2   = (const float*)d_in[28];
  const float* clsc_b2   = (const float*)d_in[29];
  const float* clsm_W1   = (const float*)d_in[30];
  const float* clsm_b1   = (const float*)d_in[31];
  const float* clsm_W2   = (const float*)d_in[32];
  const float* clsm_b2   = (const float*)d_in[33];
  const float* risk_W1   = (const float*)d_in[34];
  const float* risk_b1   = (const float*)d_in[35];
  const float* risk_W2   = (const float*)d_in[36];
  const float* risk_b2   = (const float*)d_in[37];
  const int*   cm_src    = (const int*)d_in[38];
  const int*   cm_dst    = (const int*)d_in[39];
  const int*   mc_src    = (const int*)d_in[40];
  const int*   mc_dst    = (const int*)d_in[41];
  float* out = (float*)d_out;

  // workspace carve-up (~132 MB); every array re-derived each launch
  float* base = (float*)d_ws;
  size_t o = 0;
  auto alloc = [&](size_t n) { float* p = base + o; o += (n + 3) & ~size_t(3); return p; };
  float* hs_card = alloc((size_t)NC * 128);   // hs (L0/L1), then MLP hidden (cards)
  float* xc1     = alloc((size_t)NC * 128);   // xc1, then xc2raw
  float* hs_mer  = alloc((size_t)NM * 128);
  float* xm1     = alloc((size_t)NM * 128);
  float* as_card = alloc((size_t)NC * 4);
  float* ad_card = alloc((size_t)NC * 4);
  float* as_mer  = alloc((size_t)NM * 4);
  float* ad_mer  = alloc((size_t)NM * 4);
  float* v_l0cm  = alloc(512);
  float* v_l0mc  = alloc(512);
  float* v_l1cm  = alloc(512);
  float* v_l1mc  = alloc(512);
  float* WcatC   = alloc(128 * 128);
  float* bC      = alloc(128);
  float* WcatM   = alloc(128 * 128);
  float* bM      = alloc(128);
  float* logc    = alloc(NC);
  float* logm    = alloc(NM);
  float* pmaxc   = alloc(NC / 4);
  float* pmaxm   = alloc(NM / 4);
  float* stats   = alloc(4);                  // [maxc, maxm, denc, denm]
  int* cnt_cm  = (int*)alloc(NM);             // cnt_cm & cnt_mc contiguous (one zero pass)
  int* cnt_mc  = (int*)alloc(NC);
  int* offs_cm = (int*)alloc(NM + 1);
  int* offs_mc = (int*)alloc(NC + 1);
  int* cur_cm  = (int*)alloc(NM);
  int* cur_mc  = (int*)alloc(NC);
  int* parts   = (int*)alloc(128);
  int* csr_cm  = (int*)alloc(NE);
  int* csr_mc  = (int*)alloc(NE);

  const dim3 B256(256);
  k_zero<<<dim3(256), B256, 0, stream>>>(cnt_cm, NM + NC, (int*)stats, 4);
  k_prepv<<<dim3(4), dim3(128), 0, stream>>>(l0cm_Wdst, l0cm_adst, v_l0cm,
                                             l0mc_Wdst, l0mc_adst, v_l0mc,
                                             l1cm_Wdst, l1cm_adst, v_l1cm,
                                             l1mc_Wdst, l1mc_adst, v_l1mc);
  k_prepw<<<dim3(64), B256, 0, stream>>>(clsc_W1, clsc_b1, clsm_W1, clsm_b1,
                                         risk_W1, risk_b1, WcatC, bC, WcatM, bM);
  k_hist<<<dim3(512), B256, 0, stream>>>(cm_dst, mc_dst, cnt_cm, cnt_mc);
  k_scan1<<<dim3(118), B256, 0, stream>>>(cnt_cm, cnt_mc, offs_cm, offs_mc, parts);
  k_scan2<<<dim3(2), B256, 0, stream>>>(parts);
  k_scan3<<<dim3(469), B256, 0, stream>>>(offs_cm, offs_mc, cur_cm, cur_mc, parts);
  k_scatter<<<dim3(512), B256, 0, stream>>>(cm_src, cm_dst, mc_src, mc_dst,
                                            cur_cm, cur_mc, csr_cm, csr_mc);
  const int gA = (NC + 63) / 64;   // 1563
  const int gB = (NM + 63) / 64;   // 313
  // ---- layer 0
  k_gemm<64, 0><<<dim3(gA + gB), B256, 0, stream>>>(
      x_card, l0cm_Wsrc, l0cm_asrc, v_l0mc, hs_card, as_card, ad_card,
      nullptr, nullptr, nullptr, nullptr, NC, gA,
      x_mer, l0mc_Wsrc, l0mc_asrc, v_l0cm, hs_mer, as_mer, ad_mer,
      nullptr, nullptr, nullptr, nullptr, NM);
  k_agg<<<dim3(NM + NC), dim3(128), 0, stream>>>(
      offs_cm, csr_cm, as_card, ad_mer, hs_card, l0cm_b, xm1, NM,
      offs_mc, csr_mc, as_mer, ad_card, hs_mer, l0mc_b, xc1);
  // ---- layer 1
  k_gemm<128, 0><<<dim3(gA + gB), B256, 0, stream>>>(
      xc1, l1cm_Wsrc, l1cm_asrc, v_l1mc, hs_card, as_card, ad_card,
      nullptr, nullptr, nullptr, nullptr, NC, gA,
      xm1, l1mc_Wsrc, l1mc_asrc, v_l1cm, hs_mer, as_mer, ad_mer,
      nullptr, nullptr, nullptr, nullptr, NM);
  k_agg<<<dim3(NM + NC), dim3(128), 0, stream>>>(
      offs_cm, csr_cm, as_card, ad_mer, hs_card, l1cm_b, xm1, NM,   // xm2raw -> xm1 buf
      offs_mc, csr_mc, as_mer, ad_card, hs_mer, l1mc_b, xc1);       // xc2raw -> xc1 buf
  // ---- global node softmax
  k_logits<<<dim3(NC / 4 + NM / 4), B256, 0, stream>>>(
      xc1, xm1, attw_c, attb_c, attw_m, attb_m, logc, logm, pmaxc, pmaxm);
  k_stats<<<dim3(2), dim3(1024), 0, stream>>>(pmaxc, pmaxm, stats);
  k_expsum<<<dim3(320), B256, 0, stream>>>(logc, logm, stats);
  // ---- MLP hidden (cls||risk) with per-row scale; also emits xc2/xm2 outputs
  k_gemm<128, 1><<<dim3(gA + gB), B256, 0, stream>>>(
      xc1, WcatC, nullptr, nullptr, hs_card, nullptr, nullptr,
      bC, logc, stats + 2, out, NC, gA,
      xm1, WcatM, nullptr, nullptr, hs_mer, nullptr, nullptr,
      bM, logm, stats + 3, out + OFF_XM2, NM);
  k_heads<<<dim3(NC / 4 + NM / 4), B256, 0, stream>>>(
      hs_card, hs_mer, clsc_W2, clsc_b2, clsm_W2, clsm_b2, risk_W2, risk_b2, out);
}

// Round 2
// 719.371 us; speedup vs baseline: 1.1744x; 1.1744x over previous
//
#include <hip/hip_runtime.h>

typedef _Float16 f16;
typedef _Float16 f16x2 __attribute__((ext_vector_type(2)));
typedef _Float16 f16x4 __attribute__((ext_vector_type(4)));

// Problem constants (fixed by the reference)
constexpr int NC = 100000;   // cards
constexpr int NM = 20000;    // merchants
constexpr int NE = 400000;   // edges per edge-type

// d_out layout (floats), concat of (xc2, xm2, pred_c, pred_m, risk_c, risk_m)
constexpr int OFF_XM2 = NC * 128;            // 12,800,000
constexpr int OFF_PC  = OFF_XM2 + NM * 128;  // 15,360,000
constexpr int OFF_PM  = OFF_PC + NC * 2;     // 15,560,000
constexpr int OFF_RC  = OFF_PM + NM * 2;     // 15,600,000
constexpr int OFF_RM  = OFF_RC + NC;         // 15,700,000

// ---------------------------------------------------------------- fused prep
// blocks 0..255: zero counters+stats. blocks 256..259: a_d GEMV vectors.
// blocks 260..323: concat cls_W1 || risk_W1.
__global__ void __launch_bounds__(256) k_prep(
    int* zero_base, int nzero, int* stats_i,
    const float* W0, const float* a0, float* v0,
    const float* W1, const float* a1, float* v1,
    const float* W2, const float* a2, float* v2,
    const float* W3, const float* a3, float* v3,
    const float* c1, const float* cb1, const float* m1, const float* mb1,
    const float* r1, const float* rb1,
    float* WcatC, float* bC, float* WcatM, float* bM) {
  int b = blockIdx.x, t = threadIdx.x;
  if (b < 256) {
    for (int i = b * 256 + t; i < nzero + 4; i += 256 * 256) {
      if (i < nzero) zero_base[i] = 0; else stats_i[i - nzero] = 0;
    }
  } else if (b < 260) {
    const float* W; const float* a; float* v; int K;
    switch (b - 256) {
      case 0:  W = W0; a = a0; v = v0; K = 64;  break;
      case 1:  W = W1; a = a1; v = v1; K = 64;  break;
      case 2:  W = W2; a = a2; v = v2; K = 128; break;
      default: W = W3; a = a3; v = v3; K = 128; break;
    }
    for (int idx = t; idx < K * 4; idx += 256) {
      int k = idx >> 2, h = idx & 3;
      float s = 0.f;
      for (int c = 0; c < 32; ++c) s += W[k * 128 + h * 32 + c] * a[h * 32 + c];
      v[idx] = s;
    }
  } else {
    int i = (b - 260) * 256 + t;
    if (i < 128 * 128) {
      int k = i >> 7, col = i & 127;
      WcatC[i] = (col < 64) ? c1[k * 64 + col] : r1[k * 64 + (col - 64)];
      WcatM[i] = (col < 64) ? m1[k * 64 + col] : r1[k * 64 + (col - 64)];
    }
    if (i < 128) {
      bC[i] = (i < 64) ? cb1[i] : rb1[i - 64];
      bM[i] = (i < 64) ? mb1[i] : rb1[i - 64];
    }
  }
}

// ---------------------------------------------------------------- CSR build
__global__ void k_hist(const int* cm_dst, const int* mc_dst, int* cnt_cm, int* cnt_mc) {
  int i = blockIdx.x * blockDim.x + threadIdx.x;
  int stride = gridDim.x * blockDim.x;
  for (; i < NE; i += stride) {
    atomicAdd(&cnt_cm[cm_dst[i]], 1);
    atomicAdd(&cnt_mc[mc_dst[i]], 1);
  }
}

// 1024-element chunks: local exclusive scan -> offs, chunk total -> parts
// parts[0..19] = cm chunks, parts[20..117] = mc chunks
__global__ void __launch_bounds__(256) k_scan1(const int* cnt_cm, const int* cnt_mc,
                                               int* offs_cm, int* offs_mc, int* parts) {
  int b = blockIdx.x;
  const int* cnt; int* offs; int n, chunk;
  if (b < 20) { cnt = cnt_cm; offs = offs_cm; n = NM; chunk = b; }
  else        { cnt = cnt_mc; offs = offs_mc; n = NC; chunk = b - 20; }
  int t = threadIdx.x;
  int base = chunk * 1024;
  int v[4]; int tsum = 0;
  #pragma unroll
  for (int j = 0; j < 4; ++j) {
    int idx = base + t * 4 + j;
    v[j] = (idx < n) ? cnt[idx] : 0;
    tsum += v[j];
  }
  __shared__ int sd[256];
  sd[t] = tsum; __syncthreads();
  for (int off = 1; off < 256; off <<= 1) {
    int x = (t >= off) ? sd[t - off] : 0;
    __syncthreads();
    sd[t] += x;
    __syncthreads();
  }
  int excl = sd[t] - tsum;
  int r = excl;
  #pragma unroll
  for (int j = 0; j < 4; ++j) {
    int idx = base + t * 4 + j;
    if (idx < n) offs[idx] = r;
    r += v[j];
  }
  if (t == 0) parts[b] = sd[255];
}

__global__ void __launch_bounds__(256) k_scan2(int* parts) {
  int b = blockIdx.x;
  int base = (b == 0) ? 0 : 20;
  int n = (b == 0) ? 20 : 98;
  int t = threadIdx.x;
  __shared__ int sd[128];
  int v = 0;
  if (t < 128) { v = (t < n) ? parts[base + t] : 0; sd[t] = v; }
  __syncthreads();
  for (int off = 1; off < 128; off <<= 1) {
    int x = 0;
    if (t < 128 && t >= off) x = sd[t - off];
    __syncthreads();
    if (t < 128) sd[t] += x;
    __syncthreads();
  }
  if (t < 128 && t < n) parts[base + t] = sd[t] - v;
}

__global__ void k_scan3(int* offs_cm, int* offs_mc, int* cur_cm, int* cur_mc, const int* parts) {
  int i = blockIdx.x * blockDim.x + threadIdx.x;
  if (i < NM) {
    int val = offs_cm[i] + parts[i >> 10];
    offs_cm[i] = val; cur_cm[i] = val;
  } else if (i < NM + NC) {
    int j = i - NM;
    int val = offs_mc[j] + parts[20 + (j >> 10)];
    offs_mc[j] = val; cur_mc[j] = val;
  }
  if (i == 0) { offs_cm[NM] = NE; offs_mc[NC] = NE; }
}

__global__ void k_scatter(const int* cm_src, const int* cm_dst,
                          const int* mc_src, const int* mc_dst,
                          int* cur_cm, int* cur_mc, int* csr_cm, int* csr_mc) {
  int i = blockIdx.x * blockDim.x + threadIdx.x;
  int stride = gridDim.x * blockDim.x;
  for (; i < NE; i += stride) {
    int p = atomicAdd(&cur_cm[cm_dst[i]], 1);
    csr_cm[p] = cm_src[i];
    int q = atomicAdd(&cur_mc[mc_dst[i]], 1);
    csr_mc[q] = mc_src[i];
  }
}

// ---------------------------------------------------------------- GEMM
// 64-row x 128-col tile per 256-thread block.
// EPI=0: hs(f16) = x@W; epilogue computes a_s (asrc reduce) and a_d (x@v GEMV).
// EPI=1: h(f32)  = relu(w_row * (x@W) + bias); also writes outx = x * w_row
//        where w_row = wnum[row] / den[0].
template<int K, int EPI>
__global__ void __launch_bounds__(256) k_gemm(
    const float* __restrict__ xA, const float* __restrict__ WA,
    const float* __restrict__ asrcA, const float* __restrict__ vA,
    void* __restrict__ hsA, float* __restrict__ asOutA, float* __restrict__ adOutA,
    const float* __restrict__ biasA, const float* __restrict__ wnumA,
    const float* __restrict__ denA, float* __restrict__ outxA, int MA, int gridA,
    const float* __restrict__ xB, const float* __restrict__ WB,
    const float* __restrict__ asrcB, const float* __restrict__ vB,
    void* __restrict__ hsB, float* __restrict__ asOutB, float* __restrict__ adOutB,
    const float* __restrict__ biasB, const float* __restrict__ wnumB,
    const float* __restrict__ denB, float* __restrict__ outxB, int MB) {
  constexpr int P = K + 4;         // padded LDS pitch (16B-aligned, breaks bank stride)
  constexpr int F4 = K / 4;
  __shared__ float xs[64 * P];
  const float *x, *W, *asrc, *v, *bias, *wnum, *den;
  void* hs; float *asO, *adO, *outx;
  int M, blk;
  if ((int)blockIdx.x < gridA) {
    x = xA; W = WA; asrc = asrcA; v = vA; hs = hsA; asO = asOutA; adO = adOutA;
    bias = biasA; wnum = wnumA; den = denA; outx = outxA; M = MA; blk = (int)blockIdx.x;
  } else {
    x = xB; W = WB; asrc = asrcB; v = vB; hs = hsB; asO = asOutB; adO = adOutB;
    bias = biasB; wnum = wnumB; den = denB; outx = outxB; M = MB; blk = (int)blockIdx.x - gridA;
  }
  const int row0 = blk * 64;
  const int t = (int)threadIdx.x;
  // stage x tile (64 x K) into LDS, float4 loads
  const float4* x4 = reinterpret_cast<const float4*>(x);
  #pragma unroll
  for (int ii = 0; ii < (64 * F4) / 256; ++ii) {
    int idx = t + ii * 256;
    int r = idx / F4, f = idx % F4;
    int gr = row0 + r;
    float4 val = {0.f, 0.f, 0.f, 0.f};
    if (gr < M) val = x4[gr * F4 + f];
    *reinterpret_cast<float4*>(&xs[r * P + f * 4]) = val;
  }
  __syncthreads();
  const int tx = t & 31, ty = t >> 5;     // tx: col group (4 cols), ty: row group (8 rows)
  float4 acc[8];
  #pragma unroll
  for (int r = 0; r < 8; ++r) acc[r] = {0.f, 0.f, 0.f, 0.f};
  const float4* W4 = reinterpret_cast<const float4*>(W);
  for (int kk = 0; kk < K; kk += 4) {
    float4 w0 = W4[(kk + 0) * 32 + tx];
    float4 w1 = W4[(kk + 1) * 32 + tx];
    float4 w2 = W4[(kk + 2) * 32 + tx];
    float4 w3 = W4[(kk + 3) * 32 + tx];
    #pragma unroll
    for (int r = 0; r < 8; ++r) {
      float4 xv = *reinterpret_cast<const float4*>(&xs[(ty * 8 + r) * P + kk]);
      acc[r].x += xv.x * w0.x + xv.y * w1.x + xv.z * w2.x + xv.w * w3.x;
      acc[r].y += xv.x * w0.y + xv.y * w1.y + xv.z * w2.y + xv.w * w3.y;
      acc[r].z += xv.x * w0.z + xv.y * w1.z + xv.z * w2.z + xv.w * w3.z;
      acc[r].w += xv.x * w0.w + xv.y * w1.w + xv.z * w2.w + xv.w * w3.w;
    }
  }
  if constexpr (EPI == 0) {
    // store hs in fp16 (consumed by the gather kernel)
    f16* hs16 = reinterpret_cast<f16*>(hs);
    #pragma unroll
    for (int r = 0; r < 8; ++r) {
      int gr = row0 + ty * 8 + r;
      if (gr < M) {
        f16x4 p;
        p.x = (f16)acc[r].x; p.y = (f16)acc[r].y;
        p.z = (f16)acc[r].z; p.w = (f16)acc[r].w;
        *reinterpret_cast<f16x4*>(&hs16[(size_t)gr * 128 + tx * 4]) = p;
      }
    }
    // epilogue: a_s (reduce acc with asrc) and a_d (x@v GEMV) per head
    const int h = tx >> 3, sl = tx & 7;
    float asv[4];
    #pragma unroll
    for (int j = 0; j < 4; ++j) asv[j] = asrc[h * 32 + sl * 4 + j];
    constexpr int SL = K / 8;
    #pragma unroll
    for (int r = 0; r < 8; ++r) {
      int row = ty * 8 + r;
      float p = acc[r].x * asv[0] + acc[r].y * asv[1] + acc[r].z * asv[2] + acc[r].w * asv[3];
      float q = 0.f;
      #pragma unroll
      for (int k2 = 0; k2 < SL; ++k2) {
        int k = sl * SL + k2;
        q += xs[row * P + k] * v[k * 4 + h];
      }
      #pragma unroll
      for (int m = 1; m < 8; m <<= 1) { p += __shfl_xor(p, m); q += __shfl_xor(q, m); }
      int gr = row0 + row;
      if (sl == 0 && gr < M) { asO[gr * 4 + h] = p; adO[gr * 4 + h] = q; }
    }
  } else {
    float* hsf = reinterpret_cast<float*>(hs);
    const float invden = 1.0f / den[0];
    const float4 b4 = *reinterpret_cast<const float4*>(&bias[tx * 4]);
    #pragma unroll
    for (int r = 0; r < 8; ++r) {
      int gr = row0 + ty * 8 + r;
      if (gr < M) {
        float w = wnum[gr] * invden;
        float4 o;
        o.x = fmaxf(acc[r].x * w + b4.x, 0.f);
        o.y = fmaxf(acc[r].y * w + b4.y, 0.f);
        o.z = fmaxf(acc[r].z * w + b4.z, 0.f);
        o.w = fmaxf(acc[r].w * w + b4.w, 0.f);
        *reinterpret_cast<float4*>(&hsf[(size_t)gr * 128 + tx * 4]) = o;
      }
    }
    // also emit the reweighted node features (xc2/xm2 outputs) from the LDS tile
    #pragma unroll
    for (int ii = 0; ii < 8; ++ii) {          // 64 rows * 32 float4 = 2048 / 256
      int idx = t + ii * 256;
      int r = idx >> 5, f = idx & 31;
      int gr = row0 + r;
      if (gr < M) {
        float w = wnum[gr] * invden;
        float4 xv = *reinterpret_cast<const float4*>(&xs[r * P + f * 4]);
        xv.x *= w; xv.y *= w; xv.z *= w; xv.w *= w;
        *reinterpret_cast<float4*>(&outx[gr * 128 + f * 4]) = xv;
      }
    }
  }
}

// ---------------------------------------------------------------- aggregation
// One 128-thread block (2 waves) per destination node. Online softmax over
// 32-edge chunks: weight phase computes each (edge,head) e/exp exactly once
// (thread = edge(t&31) x head(t>>5)), parks w+src in LDS; gather phase: wave
// gw handles edges j==gw (mod 2), lane l gathers fp16x2 channels (2l,2l+1).
__global__ void __launch_bounds__(128) k_agg(
    const int* __restrict__ offsA, const int* __restrict__ csrA,
    const float* __restrict__ asA, const float* __restrict__ adA,
    const f16* __restrict__ hsA, const float* __restrict__ biasA,
    float* __restrict__ outA, int ndstA,
    const int* __restrict__ offsB, const int* __restrict__ csrB,
    const float* __restrict__ asB, const float* __restrict__ adB,
    const f16* __restrict__ hsB, const float* __restrict__ biasB,
    float* __restrict__ outB) {
  const int* offs; const int* csr; const float* as_; const float* ad;
  const f16* hsp; const float* bias; float* out; int d;
  if ((int)blockIdx.x < ndstA) {
    offs = offsA; csr = csrA; as_ = asA; ad = adA; hsp = hsA; bias = biasA; out = outA;
    d = (int)blockIdx.x;
  } else {
    offs = offsB; csr = csrB; as_ = asB; ad = adB; hsp = hsB; bias = biasB; out = outB;
    d = (int)blockIdx.x - ndstA;
  }
  const int t = (int)threadIdx.x;
  const int wi = t & 31, wh = t >> 5;        // weight-role: edge-in-chunk, head
  const int gw = t >> 6, gl = t & 63;        // gather-role: wave, lane
  const int gh = gl >> 4;                    // gather channel-pair head
  const int beg = offs[d], end = offs[d + 1];
  __shared__ int   sbuf[32];
  __shared__ float wbuf[128];
  __shared__ float shead[8];                 // [0..3] scale, [4..7] den
  __shared__ float2 accbuf[64];
  const float adv = ad[d * 4 + wh];
  float m_run = -1e30f, den = 0.f;
  float2 acc = {0.f, 0.f};
  for (int base = beg; base < end; base += 32) {
    const int n = min(32, end - base);
    float e = -1e30f; int s = 0;
    if (wi < n) {
      s = csr[base + wi];
      float ev = as_[s * 4 + wh] + adv;
      e = (ev > 0.f) ? ev : 0.2f * ev;
    }
    float cm = e;
    #pragma unroll
    for (int msk = 1; msk < 32; msk <<= 1) cm = fmaxf(cm, __shfl_xor(cm, msk, 32));
    const float m_new = fmaxf(m_run, cm);
    const float scale = __expf(m_run - m_new);   // 0 on first chunk (m_run=-1e30)
    const float w = __expf(e - m_new);           // 0 for invalid lanes
    float ws = w;
    #pragma unroll
    for (int msk = 1; msk < 32; msk <<= 1) ws += __shfl_xor(ws, msk, 32);
    den = den * scale + ws;
    m_run = m_new;
    wbuf[wh * 32 + wi] = w;
    if (wh == 0 && wi < n) sbuf[wi] = s;
    if (wi == 0) shead[wh] = scale;
    __syncthreads();
    const float sc = shead[gh];
    acc.x *= sc; acc.y *= sc;
    for (int j = gw; j < n; j += 2) {
      const int ss = sbuf[j];
      const float wj = wbuf[gh * 32 + j];
      const f16x2 hv = *reinterpret_cast<const f16x2*>(&hsp[ss * 128 + gl * 2]);
      acc.x += wj * (float)hv.x;
      acc.y += wj * (float)hv.y;
    }
    __syncthreads();
  }
  if (wi == 0) shead[4 + wh] = den;
  if (gw == 1) accbuf[gl] = acc;
  __syncthreads();
  if (gw == 0) {
    const float dh = shead[4 + gh];
    const float invden = (dh > 0.f) ? 1.f / dh : 0.f;
    const float2 a1 = accbuf[gl];
    const float2 b2 = *reinterpret_cast<const float2*>(&bias[gl * 2]);
    float2 o;
    o.x = (acc.x + a1.x) * invden + b2.x;
    o.y = (acc.y + a1.y) * invden + b2.y;
    *reinterpret_cast<float2*>(&out[d * 128 + gl * 2]) = o;
  }
}

// ---------------------------------------------------------------- global softmax + heads
__global__ void __launch_bounds__(256) k_logits(
    const float* __restrict__ xc2, const float* __restrict__ xm2,
    const float* __restrict__ attwc, const float* __restrict__ attbc,
    const float* __restrict__ attwm, const float* __restrict__ attbm,
    float* __restrict__ logc, float* __restrict__ logm,
    float* __restrict__ pmaxc, float* __restrict__ pmaxm) {
  const int NBC = NC / 4;
  bool card = (int)blockIdx.x < NBC;
  int wave = threadIdx.x >> 6, lane = threadIdx.x & 63;
  int n = card ? ((int)blockIdx.x * 4 + wave) : (((int)blockIdx.x - NBC) * 4 + wave);
  const float* x2 = card ? xc2 : xm2;
  const float* aw = card ? attwc : attwm;
  float b = card ? attbc[0] : attbm[0];
  float* logv = card ? logc : logm;
  float s = x2[n * 128 + lane] * aw[lane] + x2[n * 128 + 64 + lane] * aw[64 + lane];
  #pragma unroll
  for (int m = 1; m < 64; m <<= 1) s += __shfl_xor(s, m);
  __shared__ float sl_[4];
  float logit = s + b;
  if (lane == 0) { logv[n] = logit; sl_[wave] = logit; }
  __syncthreads();
  if (threadIdx.x == 0) {
    float mx = fmaxf(fmaxf(sl_[0], sl_[1]), fmaxf(sl_[2], sl_[3]));
    if (card) pmaxc[blockIdx.x] = mx; else pmaxm[blockIdx.x - NBC] = mx;
  }
}

__global__ void __launch_bounds__(1024) k_stats(const float* pmaxc, const float* pmaxm, float* stats) {
  const float* src = (blockIdx.x == 0) ? pmaxc : pmaxm;
  int n = (blockIdx.x == 0) ? NC / 4 : NM / 4;
  float m = -1e30f;
  for (int i = threadIdx.x; i < n; i += 1024) m = fmaxf(m, src[i]);
  __shared__ float sd[1024];
  sd[threadIdx.x] = m; __syncthreads();
  for (int off = 512; off > 0; off >>= 1) {
    if ((int)threadIdx.x < off) sd[threadIdx.x] = fmaxf(sd[threadIdx.x], sd[threadIdx.x + off]);
    __syncthreads();
  }
  if (threadIdx.x == 0) stats[blockIdx.x] = sd[0];
}

__global__ void __launch_bounds__(256) k_expsum(float* logc, float* logm, float* stats) {
  bool card = (int)blockIdx.x < 256;
  float* logv = card ? logc : logm;
  int n = card ? NC : NM;
  float mx = card ? stats[0] : stats[1];
  int b0 = card ? (int)blockIdx.x : (int)blockIdx.x - 256;
  int nb = card ? 256 : 64;
  float local = 0.f;
  for (int i = b0 * 256 + (int)threadIdx.x; i < n; i += nb * 256) {
    float e = __expf(logv[i] - mx);
    logv[i] = e;        // store numerator for later
    local += e;
  }
  __shared__ float sd[256];
  sd[threadIdx.x] = local; __syncthreads();
  for (int off = 128; off > 0; off >>= 1) {
    if ((int)threadIdx.x < off) sd[threadIdx.x] += sd[threadIdx.x + off];
    __syncthreads();
  }
  if (threadIdx.x == 0) atomicAdd(card ? &stats[2] : &stats[3], sd[0]);
}

__global__ void __launch_bounds__(256) k_heads(
    const float* __restrict__ hC, const float* __restrict__ hM,
    const float* __restrict__ w2c, const float* __restrict__ b2c,
    const float* __restrict__ w2m, const float* __restrict__ b2m,
    const float* __restrict__ w2r, const float* __restrict__ b2r,
    float* __restrict__ out) {
  const int NBC = NC / 4;
  bool card = (int)blockIdx.x < NBC;
  int wave = threadIdx.x >> 6, lane = threadIdx.x & 63;
  int n = card ? ((int)blockIdx.x * 4 + wave) : (((int)blockIdx.x - NBC) * 4 + wave);
  const float* h = card ? hC : hM;
  const float* W2 = card ? w2c : w2m;
  const float* B2 = card ? b2c : b2m;
  float hc = h[n * 128 + lane];        // cls hidden (already relu'd)
  float hr = h[n * 128 + 64 + lane];   // risk hidden
  float p0 = hc * W2[lane * 2 + 0];
  float p1 = hc * W2[lane * 2 + 1];
  float rr = hr * w2r[lane];
  #pragma unroll
  for (int m = 1; m < 64; m <<= 1) {
    p0 += __shfl_xor(p0, m);
    p1 += __shfl_xor(p1, m);
    rr += __shfl_xor(rr, m);
  }
  if (lane == 0) {
    float* pout = out + (card ? OFF_PC : OFF_PM);
    float* rout = out + (card ? OFF_RC : OFF_RM);
    pout[n * 2 + 0] = p0 + B2[0];
    pout[n * 2 + 1] = p1 + B2[1];
    float z = rr + b2r[0];
    rout[n] = 1.f / (1.f + __expf(-z));
  }
}

// ---------------------------------------------------------------- launch
extern "C" void kernel_launch(void* const* d_in, const int* in_sizes, int n_in,
                              void* d_out, int out_size, void* d_ws, size_t ws_size,
                              hipStream_t stream) {
  (void)in_sizes; (void)n_in; (void)out_size; (void)ws_size;
  const float* x_card    = (const float*)d_in[0];
  const float* x_mer     = (const float*)d_in[1];
  const float* l0cm_Wsrc = (const float*)d_in[2];
  const float* l0cm_Wdst = (const float*)d_in[3];
  const float* l0cm_asrc = (const float*)d_in[4];
  const float* l0cm_adst = (const float*)d_in[5];
  const float* l0cm_b    = (const float*)d_in[6];
  const float* l0mc_Wsrc = (const float*)d_in[7];
  const float* l0mc_Wdst = (const float*)d_in[8];
  const float* l0mc_asrc = (const float*)d_in[9];
  const float* l0mc_adst = (const float*)d_in[10];
  const float* l0mc_b    = (const float*)d_in[11];
  const float* l1cm_Wsrc = (const float*)d_in[12];
  const float* l1cm_Wdst = (const float*)d_in[13];
  const float* l1cm_asrc = (const float*)d_in[14];
  const float* l1cm_adst = (const float*)d_in[15];
  const float* l1cm_b    = (const float*)d_in[16];
  const float* l1mc_Wsrc = (const float*)d_in[17];
  const float* l1mc_Wdst = (const float*)d_in[18];
  const float* l1mc_asrc = (const float*)d_in[19];
  const float* l1mc_adst = (const float*)d_in[20];
  const float* l1mc_b    = (const float*)d_in[21];
  const float* attw_c    = (const float*)d_in[22];
  const float* attb_c    = (const float*)d_in[23];
  const float* attw_m    = (const float*)d_in[24];
  const float* attb_m    = (const float*)d_in[25];
  const float* clsc_W1   = (const float*)d_in[26];
  const float* clsc_b1   = (const float*)d_in[27];
  const float* clsc_W2   = (const float*)d_in[28];
  const float* clsc_b2   = (const float*)d_in[29];
  const float* clsm_W1   = (const float*)d_in[30];
  const float* clsm_b1   = (const float*)d_in[31];
  const float* clsm_W2   = (const float*)d_in[32];
  const float* clsm_b2   = (const float*)d_in[33];
  const float* risk_W1   = (const float*)d_in[34];
  const float* risk_b1   = (const float*)d_in[35];
  const float* risk_W2   = (const float*)d_in[36];
  const float* risk_b2   = (const float*)d_in[37];
  const int*   cm_src    = (const int*)d_in[38];
  const int*   cm_dst    = (const int*)d_in[39];
  const int*   mc_src    = (const int*)d_in[40];
  const int*   mc_dst    = (const int*)d_in[41];
  float* out = (float*)d_out;

  // workspace carve-up; every array re-derived each launch
  float* base = (float*)d_ws;
  size_t o = 0;
  auto alloc = [&](size_t n) { float* p = base + o; o += (n + 3) & ~size_t(3); return p; };
  float* hs_card = alloc((size_t)NC * 128);   // hs f16 (L0/L1), then MLP hidden f32 (cards)
  float* xc1     = alloc((size_t)NC * 128);   // xc1, then xc2raw
  float* hs_mer  = alloc((size_t)NM * 128);
  float* xm1     = alloc((size_t)NM * 128);
  float* as_card = alloc((size_t)NC * 4);
  float* ad_card = alloc((size_t)NC * 4);
  float* as_mer  = alloc((size_t)NM * 4);
  float* ad_mer  = alloc((size_t)NM * 4);
  float* v_l0cm  = alloc(512);
  float* v_l0mc  = alloc(512);
  float* v_l1cm  = alloc(512);
  float* v_l1mc  = alloc(512);
  float* WcatC   = alloc(128 * 128);
  float* bC      = alloc(128);
  float* WcatM   = alloc(128 * 128);
  float* bM      = alloc(128);
  float* logc    = alloc(NC);
  float* logm    = alloc(NM);
  float* pmaxc   = alloc(NC / 4);
  float* pmaxm   = alloc(NM / 4);
  float* stats   = alloc(4);                  // [maxc, maxm, denc, denm]
  int* cnt_cm  = (int*)alloc(NM);             // cnt_cm & cnt_mc contiguous (one zero pass)
  int* cnt_mc  = (int*)alloc(NC);
  int* offs_cm = (int*)alloc(NM + 1);
  int* offs_mc = (int*)alloc(NC + 1);
  int* cur_cm  = (int*)alloc(NM);
  int* cur_mc  = (int*)alloc(NC);
  int* parts   = (int*)alloc(128);
  int* csr_cm  = (int*)alloc(NE);
  int* csr_mc  = (int*)alloc(NE);

  const dim3 B256(256);
  k_prep<<<dim3(324), B256, 0, stream>>>(
      cnt_cm, NM + NC, (int*)stats,
      l0cm_Wdst, l0cm_adst, v_l0cm, l0mc_Wdst, l0mc_adst, v_l0mc,
      l1cm_Wdst, l1cm_adst, v_l1cm, l1mc_Wdst, l1mc_adst, v_l1mc,
      clsc_W1, clsc_b1, clsm_W1, clsm_b1, risk_W1, risk_b1,
      WcatC, bC, WcatM, bM);
  k_hist<<<dim3(512), B256, 0, stream>>>(cm_dst, mc_dst, cnt_cm, cnt_mc);
  k_scan1<<<dim3(118), B256, 0, stream>>>(cnt_cm, cnt_mc, offs_cm, offs_mc, parts);
  k_scan2<<<dim3(2), B256, 0, stream>>>(parts);
  k_scan3<<<dim3(469), B256, 0, stream>>>(offs_cm, offs_mc, cur_cm, cur_mc, parts);
  k_scatter<<<dim3(512), B256, 0, stream>>>(cm_src, cm_dst, mc_src, mc_dst,
                                            cur_cm, cur_mc, csr_cm, csr_mc);
  const int gA = (NC + 63) / 64;   // 1563
  const int gB = (NM + 63) / 64;   // 313
  // ---- layer 0
  k_gemm<64, 0><<<dim3(gA + gB), B256, 0, stream>>>(
      x_card, l0cm_Wsrc, l0cm_asrc, v_l0mc, hs_card, as_card, ad_card,
      nullptr, nullptr, nullptr, nullptr, NC, gA,
      x_mer, l0mc_Wsrc, l0mc_asrc, v_l0cm, hs_mer, as_mer, ad_mer,
      nullptr, nullptr, nullptr, nullptr, NM);
  k_agg<<<dim3(NM + NC), dim3(128), 0, stream>>>(
      offs_cm, csr_cm, as_card, ad_mer, (const f16*)hs_card, l0cm_b, xm1, NM,
      offs_mc, csr_mc, as_mer, ad_card, (const f16*)hs_mer, l0mc_b, xc1);
  // ---- layer 1
  k_gemm<128, 0><<<dim3(gA + gB), B256, 0, stream>>>(
      xc1, l1cm_Wsrc, l1cm_asrc, v_l1mc, hs_card, as_card, ad_card,
      nullptr, nullptr, nullptr, nullptr, NC, gA,
      xm1, l1mc_Wsrc, l1mc_asrc, v_l1cm, hs_mer, as_mer, ad_mer,
      nullptr, nullptr, nullptr, nullptr, NM);
  k_agg<<<dim3(NM + NC), dim3(128), 0, stream>>>(
      offs_cm, csr_cm, as_card, ad_mer, (const f16*)hs_card, l1cm_b, xm1, NM,   // xm2raw
      offs_mc, csr_mc, as_mer, ad_card, (const f16*)hs_mer, l1mc_b, xc1);       // xc2raw
  // ---- global node softmax
  k_logits<<<dim3(NC / 4 + NM / 4), B256, 0, stream>>>(
      xc1, xm1, attw_c, attb_c, attw_m, attb_m, logc, logm, pmaxc, pmaxm);
  k_stats<<<dim3(2), dim3(1024), 0, stream>>>(pmaxc, pmaxm, stats);
  k_expsum<<<dim3(320), B256, 0, stream>>>(logc, logm, stats);
  // ---- MLP hidden (cls||risk) with per-row scale; also emits xc2/xm2 outputs
  k_gemm<128, 1><<<dim3(gA + gB), B256, 0, stream>>>(
      xc1, WcatC, nullptr, nullptr, hs_card, nullptr, nullptr,
      bC, logc, stats + 2, out, NC, gA,
      xm1, WcatM, nullptr, nullptr, hs_mer, nullptr, nullptr,
      bM, logm, stats + 3, out + OFF_XM2, NM);
  k_heads<<<dim3(NC / 4 + NM / 4), B256, 0, stream>>>(
      hs_card, hs_mer, clsc_W2, clsc_b2, clsm_W2, clsm_b2, risk_W2, risk_b2, out);
}

// Round 3
// 601.682 us; speedup vs baseline: 1.4041x; 1.1956x over previous
//
#include <hip/hip_runtime.h>

typedef _Float16 f16;
typedef _Float16 f16x2 __attribute__((ext_vector_type(2)));
typedef _Float16 f16x4 __attribute__((ext_vector_type(4)));
typedef _Float16 f16x8 __attribute__((ext_vector_type(8)));
typedef float floatx4 __attribute__((ext_vector_type(4)));

// Problem constants (fixed by the reference)
constexpr int NC = 100000;   // cards
constexpr int NM = 20000;    // merchants
constexpr int NE = 400000;   // edges per edge-type

// d_out layout (floats), concat of (xc2, xm2, pred_c, pred_m, risk_c, risk_m)
constexpr int OFF_XM2 = NC * 128;
constexpr int OFF_PC  = OFF_XM2 + NM * 128;
constexpr int OFF_PM  = OFF_PC + NC * 2;
constexpr int OFF_RC  = OFF_PM + NM * 2;
constexpr int OFF_RM  = OFF_RC + NC;

// ---------------------------------------------------------------- fused prep
// blocks 0..255: zero counters+stats. block 256: a_d GEMV vectors + bias concat.
// blocks 257..276: swizzle W matrices into MFMA B-fragment fp16 order.
// B-frag layout (16x16x32): lane holds B[k=kt*32+(lane>>4)*8+j][n=ct*16+(lane&15)],
// flat: dst[((kt*8+ct)*64+lane)*8+j]
__global__ void __launch_bounds__(256) k_prep(
    int* zero_base, int nzero, int* stats_i,
    const float* W0, const float* a0, float* v0,
    const float* W1, const float* a1, float* v1,
    const float* W2, const float* a2, float* v2,
    const float* W3, const float* a3, float* v3,
    const float* cb1, const float* mb1, const float* rb1, float* bC, float* bM,
    const float* S0, const float* S1, const float* S2, const float* S3,
    const float* c1, const float* m1, const float* r1,
    f16* BfL0cm, f16* BfL0mc, f16* BfL1cm, f16* BfL1mc, f16* BfC, f16* BfM) {
  int b = blockIdx.x, t = threadIdx.x;
  if (b < 256) {
    for (int i = b * 256 + t; i < nzero + 4; i += 256 * 256) {
      if (i < nzero) zero_base[i] = 0; else stats_i[i - nzero] = 0;
    }
  } else if (b == 256) {
    const float* Wd[4] = {W0, W1, W2, W3};
    const float* ad[4] = {a0, a1, a2, a3};
    float* vd[4] = {v0, v1, v2, v3};
    for (int idx = t; idx < 1536; idx += 256) {
      int mat, base;
      if (idx < 256)       { mat = 0; base = 0; }
      else if (idx < 512)  { mat = 1; base = 256; }
      else if (idx < 1024) { mat = 2; base = 512; }
      else                 { mat = 3; base = 1024; }
      int local = idx - base, k = local >> 2, h = local & 3;
      const float* W = Wd[mat]; const float* a = ad[mat];
      float s = 0.f;
      for (int c = 0; c < 32; ++c) s += W[k * 128 + h * 32 + c] * a[h * 32 + c];
      vd[mat][local] = s;
    }
    if (t < 128) {
      bC[t] = (t < 64) ? cb1[t] : rb1[t - 64];
      bM[t] = (t < 64) ? mb1[t] : rb1[t - 64];
    }
  } else {
    int s = b - 257;
    const float* Wp = nullptr; const float* cA = nullptr; const float* cB = nullptr;
    f16* dst; int kt;
    if (s < 2)       { Wp = S0; dst = BfL0cm; kt = s; }
    else if (s < 4)  { Wp = S1; dst = BfL0mc; kt = s - 2; }
    else if (s < 8)  { Wp = S2; dst = BfL1cm; kt = s - 4; }
    else if (s < 12) { Wp = S3; dst = BfL1mc; kt = s - 8; }
    else if (s < 16) { cA = c1; cB = r1; dst = BfC; kt = s - 12; }
    else             { cA = m1; cB = r1; dst = BfM; kt = s - 16; }
    for (int e = t; e < 512; e += 256) {
      int lane = e & 63, ct = e >> 6;
      int m = lane & 15, q = lane >> 4;
      int col = ct * 16 + m;
      f16x8 frag;
      #pragma unroll
      for (int j = 0; j < 8; ++j) {
        int k = kt * 32 + q * 8 + j;
        float val = Wp ? Wp[k * 128 + col]
                       : (col < 64 ? cA[k * 64 + col] : cB[k * 64 + (col - 64)]);
        frag[j] = (f16)val;
      }
      *reinterpret_cast<f16x8*>(&dst[(size_t)((kt * 8 + ct) * 64 + lane) * 8]) = frag;
    }
  }
}

// ---------------------------------------------------------------- CSR build
__global__ void k_hist(const int* cm_dst, const int* mc_dst, int* cnt_cm, int* cnt_mc) {
  int i = blockIdx.x * blockDim.x + threadIdx.x;
  int stride = gridDim.x * blockDim.x;
  for (; i < NE; i += stride) {
    atomicAdd(&cnt_cm[cm_dst[i]], 1);
    atomicAdd(&cnt_mc[mc_dst[i]], 1);
  }
}

__global__ void __launch_bounds__(256) k_scan1(const int* cnt_cm, const int* cnt_mc,
                                               int* offs_cm, int* offs_mc, int* parts) {
  int b = blockIdx.x;
  const int* cnt; int* offs; int n, chunk;
  if (b < 20) { cnt = cnt_cm; offs = offs_cm; n = NM; chunk = b; }
  else        { cnt = cnt_mc; offs = offs_mc; n = NC; chunk = b - 20; }
  int t = threadIdx.x;
  int base = chunk * 1024;
  int v[4]; int tsum = 0;
  #pragma unroll
  for (int j = 0; j < 4; ++j) {
    int idx = base + t * 4 + j;
    v[j] = (idx < n) ? cnt[idx] : 0;
    tsum += v[j];
  }
  __shared__ int sd[256];
  sd[t] = tsum; __syncthreads();
  for (int off = 1; off < 256; off <<= 1) {
    int x = (t >= off) ? sd[t - off] : 0;
    __syncthreads();
    sd[t] += x;
    __syncthreads();
  }
  int excl = sd[t] - tsum;
  int r = excl;
  #pragma unroll
  for (int j = 0; j < 4; ++j) {
    int idx = base + t * 4 + j;
    if (idx < n) offs[idx] = r;
    r += v[j];
  }
  if (t == 0) parts[b] = sd[255];
}

__global__ void __launch_bounds__(256) k_scan2(int* parts) {
  int b = blockIdx.x;
  int base = (b == 0) ? 0 : 20;
  int n = (b == 0) ? 20 : 98;
  int t = threadIdx.x;
  __shared__ int sd[128];
  int v = 0;
  if (t < 128) { v = (t < n) ? parts[base + t] : 0; sd[t] = v; }
  __syncthreads();
  for (int off = 1; off < 128; off <<= 1) {
    int x = 0;
    if (t < 128 && t >= off) x = sd[t - off];
    __syncthreads();
    if (t < 128) sd[t] += x;
    __syncthreads();
  }
  if (t < 128 && t < n) parts[base + t] = sd[t] - v;
}

__global__ void k_scan3(int* offs_cm, int* offs_mc, int* cur_cm, int* cur_mc, const int* parts) {
  int i = blockIdx.x * blockDim.x + threadIdx.x;
  if (i < NM) {
    int val = offs_cm[i] + parts[i >> 10];
    offs_cm[i] = val; cur_cm[i] = val;
  } else if (i < NM + NC) {
    int j = i - NM;
    int val = offs_mc[j] + parts[20 + (j >> 10)];
    offs_mc[j] = val; cur_mc[j] = val;
  }
  if (i == 0) { offs_cm[NM] = NE; offs_mc[NC] = NE; }
}

__global__ void k_scatter(const int* cm_src, const int* cm_dst,
                          const int* mc_src, const int* mc_dst,
                          int* cur_cm, int* cur_mc, int* csr_cm, int* csr_mc) {
  int i = blockIdx.x * blockDim.x + threadIdx.x;
  int stride = gridDim.x * blockDim.x;
  for (; i < NE; i += stride) {
    int p = atomicAdd(&cur_cm[cm_dst[i]], 1);
    csr_cm[p] = cm_src[i];
    int q = atomicAdd(&cur_mc[mc_dst[i]], 1);
    csr_mc[q] = mc_src[i];
  }
}

// ---------------------------------------------------------------- MFMA GEMM
// 64-row x 128-col tile per 256-thread block; 4 waves, each: 16 rows x 128 cols
// via 8 col-tiles of mfma_f32_16x16x32_f16 over K/32 k-tiles.
// C/D layout: col = ct*16 + (lane&15), row = (lane>>4)*4 + reg  [verified m89]
// EPI=0: hs(f16) = x@W; epilogue: a_s (asrc . acc), a_d (x @ v GEMV from LDS).
// EPI=1: fused MLP: h = relu(wrow*(x@Wcat)+bias); pred = h_cls@W2+B2;
//        risk = sigmoid(h_risk@w2r+b2r); outx = x*wrow emitted during staging.
struct GemmSide {
  const float* x; const f16* Bf;
  const float* asrc; const float* v; f16* hs; float* asO; float* adO;   // EPI 0
  const float* bias; const float* wnum; const float* den; float* outx;  // EPI 1
  const float* W2; const float* B2; const float* w2r; const float* b2r;
  float* pred; float* risk;
  int M;
};

template<int K, int EPI>
__global__ void __launch_bounds__(256) k_gemm(GemmSide A, GemmSide B, int gridA) {
  constexpr int PP = K + 8;        // fp16 pitch; dword pitch K/2+4 (mod 32 = 4): 2-way bank alias only
  constexpr int F4 = K / 4;
  __shared__ f16 xs16[64 * PP];
  const bool isA = (int)blockIdx.x < gridA;
  GemmSide S = isA ? A : B;
  const int blk = isA ? (int)blockIdx.x : (int)blockIdx.x - gridA;
  const int rows0 = blk * 64;
  const int t = (int)threadIdx.x;
  float invden_s = 0.f;
  if constexpr (EPI == 1) invden_s = 1.0f / S.den[0];
  // stage x tile (64 x K) -> LDS fp16 (and outx = x*w for EPI=1)
  const float4* x4 = reinterpret_cast<const float4*>(S.x);
  #pragma unroll
  for (int ii = 0; ii < (64 * F4) / 256; ++ii) {
    int idx = t + ii * 256;
    int r = idx / F4, f = idx % F4;
    int gr = rows0 + r;
    float4 val = {0.f, 0.f, 0.f, 0.f};
    if (gr < S.M) val = x4[(size_t)gr * F4 + f];
    f16x4 hv; hv.x = (f16)val.x; hv.y = (f16)val.y; hv.z = (f16)val.z; hv.w = (f16)val.w;
    *reinterpret_cast<f16x4*>(&xs16[r * PP + f * 4]) = hv;
    if constexpr (EPI == 1) {
      if (gr < S.M) {
        float w = S.wnum[gr] * invden_s;
        float4 ov = {val.x * w, val.y * w, val.z * w, val.w * w};
        *reinterpret_cast<float4*>(&S.outx[(size_t)gr * 128 + f * 4]) = ov;
      }
    }
  }
  __syncthreads();
  const int lane = t & 63, w = t >> 6;
  const int m = lane & 15, q = lane >> 4;
  const int rbase = w * 16;
  floatx4 acc[8];
  #pragma unroll
  for (int ct = 0; ct < 8; ++ct) acc[ct] = {0.f, 0.f, 0.f, 0.f};
  const f16x8* Bf8 = reinterpret_cast<const f16x8*>(S.Bf);
  #pragma unroll
  for (int kt = 0; kt < K / 32; ++kt) {
    f16x8 a = *reinterpret_cast<const f16x8*>(&xs16[(rbase + m) * PP + kt * 32 + q * 8]);
    #pragma unroll
    for (int ct = 0; ct < 8; ++ct) {
      f16x8 b = Bf8[(kt * 8 + ct) * 64 + lane];
      acc[ct] = __builtin_amdgcn_mfma_f32_16x16x32_f16(a, b, acc[ct], 0, 0, 0);
    }
  }
  if constexpr (EPI == 0) {
    // ---- hs f16 store: pair columns via xor-1 shuffle, one dword store per (reg, ct-pair)
    #pragma unroll
    for (int reg = 0; reg < 4; ++reg) {
      int gr = rows0 + rbase + q * 4 + reg;
      bool ok = gr < S.M;
      #pragma unroll
      for (int cp = 0; cp < 4; ++cp) {
        float v0 = acc[2 * cp][reg], v1 = acc[2 * cp + 1][reg];
        float w0 = __shfl_xor(v0, 1), w1 = __shfl_xor(v1, 1);
        bool even = (m & 1) == 0;
        f16x2 pr;
        pr.x = (f16)(even ? v0 : w1);
        pr.y = (f16)(even ? w0 : v1);
        int col = even ? (2 * cp) * 16 + m : (2 * cp + 1) * 16 + m - 1;
        if (ok) *reinterpret_cast<f16x2*>(&S.hs[(size_t)gr * 128 + col]) = pr;
      }
    }
    // ---- a_s: per-head reduce of acc with asrc (head h covers ct = 2h, 2h+1)
    float as0[4], as1[4];
    #pragma unroll
    for (int h = 0; h < 4; ++h) { as0[h] = S.asrc[h * 32 + m]; as1[h] = S.asrc[h * 32 + 16 + m]; }
    #pragma unroll
    for (int reg = 0; reg < 4; ++reg) {
      float p[4];
      #pragma unroll
      for (int h = 0; h < 4; ++h)
        p[h] = acc[2 * h][reg] * as0[h] + acc[2 * h + 1][reg] * as1[h];
      #pragma unroll
      for (int off = 1; off < 16; off <<= 1) {
        #pragma unroll
        for (int h = 0; h < 4; ++h) p[h] += __shfl_xor(p[h], off);
      }
      int gr = rows0 + rbase + q * 4 + reg;
      if (m == 0 && gr < S.M) {
        float4 pv = {p[0], p[1], p[2], p[3]};
        *reinterpret_cast<float4*>(&S.asO[gr * 4]) = pv;
      }
    }
    // ---- a_d: GEMV x @ v from LDS (lane m = row, q = k-slice)
    float qd[4] = {0.f, 0.f, 0.f, 0.f};
    const float4* v4p = reinterpret_cast<const float4*>(S.v);
    constexpr int KS = K / 4;
    #pragma unroll
    for (int i = 0; i < KS; ++i) {
      int k = q * KS + i;
      float xv = (float)xs16[(rbase + m) * PP + k];
      float4 vk = v4p[k];
      qd[0] += xv * vk.x; qd[1] += xv * vk.y; qd[2] += xv * vk.z; qd[3] += xv * vk.w;
    }
    #pragma unroll
    for (int h = 0; h < 4; ++h) {
      qd[h] += __shfl_xor(qd[h], 16);
      qd[h] += __shfl_xor(qd[h], 32);
    }
    int gr2 = rows0 + rbase + m;
    if (q == 0 && gr2 < S.M) {
      float4 qv = {qd[0], qd[1], qd[2], qd[3]};
      *reinterpret_cast<float4*>(&S.adO[gr2 * 4]) = qv;
    }
  } else {
    // ---- fused MLP-2 + heads
    float wn[4];
    #pragma unroll
    for (int reg = 0; reg < 4; ++reg) {
      int gr = rows0 + rbase + q * 4 + reg;
      wn[reg] = (gr < S.M) ? S.wnum[gr] * invden_s : 0.f;
    }
    float bct[8], w2c0[4], w2c1[4], w2rv[4];
    #pragma unroll
    for (int ct = 0; ct < 8; ++ct) bct[ct] = S.bias[ct * 16 + m];
    #pragma unroll
    for (int ct = 0; ct < 4; ++ct) {
      int col = ct * 16 + m;
      w2c0[ct] = S.W2[col * 2];
      w2c1[ct] = S.W2[col * 2 + 1];
      w2rv[ct] = S.w2r[col];
    }
    #pragma unroll
    for (int reg = 0; reg < 4; ++reg) {
      float p0 = 0.f, p1 = 0.f, rr = 0.f;
      #pragma unroll
      for (int ct = 0; ct < 4; ++ct) {
        float hv = fmaxf(acc[ct][reg] * wn[reg] + bct[ct], 0.f);
        p0 += hv * w2c0[ct];
        p1 += hv * w2c1[ct];
      }
      #pragma unroll
      for (int ct = 4; ct < 8; ++ct) {
        float hv = fmaxf(acc[ct][reg] * wn[reg] + bct[ct], 0.f);
        rr += hv * w2rv[ct - 4];
      }
      #pragma unroll
      for (int off = 1; off < 16; off <<= 1) {
        p0 += __shfl_xor(p0, off);
        p1 += __shfl_xor(p1, off);
        rr += __shfl_xor(rr, off);
      }
      int gr = rows0 + rbase + q * 4 + reg;
      if (m == 0 && gr < S.M) {
        float2 pp = {p0 + S.B2[0], p1 + S.B2[1]};
        *reinterpret_cast<float2*>(&S.pred[gr * 2]) = pp;
        float z = rr + S.b2r[0];
        S.risk[gr] = 1.f / (1.f + __expf(-z));
      }
    }
  }
}

// ---------------------------------------------------------------- aggregation
// One 128-thread block (2 waves) per destination node; online softmax over
// 32-edge chunks. Optionally emits the graph-attention logit for its output row.
__global__ void __launch_bounds__(128) k_agg(
    const int* __restrict__ offsA, const int* __restrict__ csrA,
    const float* __restrict__ asA, const float* __restrict__ adA,
    const f16* __restrict__ hsA, const float* __restrict__ biasA,
    float* __restrict__ outA, const float* __restrict__ attwA,
    const float* __restrict__ attbA, float* __restrict__ logvA, int ndstA,
    const int* __restrict__ offsB, const int* __restrict__ csrB,
    const float* __restrict__ asB, const float* __restrict__ adB,
    const f16* __restrict__ hsB, const float* __restrict__ biasB,
    float* __restrict__ outB, const float* __restrict__ attwB,
    const float* __restrict__ attbB, float* __restrict__ logvB) {
  const int* offs; const int* csr; const float* as_; const float* ad;
  const f16* hsp; const float* bias; float* out; int d;
  const float* attw; const float* attb; float* logv;
  if ((int)blockIdx.x < ndstA) {
    offs = offsA; csr = csrA; as_ = asA; ad = adA; hsp = hsA; bias = biasA; out = outA;
    attw = attwA; attb = attbA; logv = logvA; d = (int)blockIdx.x;
  } else {
    offs = offsB; csr = csrB; as_ = asB; ad = adB; hsp = hsB; bias = biasB; out = outB;
    attw = attwB; attb = attbB; logv = logvB; d = (int)blockIdx.x - ndstA;
  }
  const int t = (int)threadIdx.x;
  const int wi = t & 31, wh = t >> 5;        // weight-role: edge-in-chunk, head
  const int gw = t >> 6, gl = t & 63;        // gather-role: wave, lane
  const int gh = gl >> 4;                    // gather channel-pair head
  const int beg = offs[d], end = offs[d + 1];
  __shared__ int   sbuf[32];
  __shared__ float wbuf[128];
  __shared__ float shead[8];                 // [0..3] scale, [4..7] den
  __shared__ float2 accbuf[64];
  const float adv = ad[d * 4 + wh];
  float m_run = -1e30f, den = 0.f;
  float2 acc = {0.f, 0.f};
  for (int base = beg; base < end; base += 32) {
    const int n = min(32, end - base);
    float e = -1e30f; int s = 0;
    if (wi < n) {
      s = csr[base + wi];
      float ev = as_[s * 4 + wh] + adv;
      e = (ev > 0.f) ? ev : 0.2f * ev;
    }
    float cm = e;
    #pragma unroll
    for (int msk = 1; msk < 32; msk <<= 1) cm = fmaxf(cm, __shfl_xor(cm, msk, 32));
    const float m_new = fmaxf(m_run, cm);
    const float scale = __expf(m_run - m_new);
    const float w = __expf(e - m_new);
    float ws = w;
    #pragma unroll
    for (int msk = 1; msk < 32; msk <<= 1) ws += __shfl_xor(ws, msk, 32);
    den = den * scale + ws;
    m_run = m_new;
    wbuf[wh * 32 + wi] = w;
    if (wh == 0 && wi < n) sbuf[wi] = s;
    if (wi == 0) shead[wh] = scale;
    __syncthreads();
    const float sc = shead[gh];
    acc.x *= sc; acc.y *= sc;
    for (int j = gw; j < n; j += 2) {
      const int ss = sbuf[j];
      const float wj = wbuf[gh * 32 + j];
      const f16x2 hv = *reinterpret_cast<const f16x2*>(&hsp[ss * 128 + gl * 2]);
      acc.x += wj * (float)hv.x;
      acc.y += wj * (float)hv.y;
    }
    __syncthreads();
  }
  if (wi == 0) shead[4 + wh] = den;
  if (gw == 1) accbuf[gl] = acc;
  __syncthreads();
  if (gw == 0) {
    const float dh = shead[4 + gh];
    const float invden = (dh > 0.f) ? 1.f / dh : 0.f;
    const float2 a1 = accbuf[gl];
    const float2 b2 = *reinterpret_cast<const float2*>(&bias[gl * 2]);
    float2 o;
    o.x = (acc.x + a1.x) * invden + b2.x;
    o.y = (acc.y + a1.y) * invden + b2.y;
    *reinterpret_cast<float2*>(&out[d * 128 + gl * 2]) = o;
    if (attw) {
      float s = o.x * attw[gl * 2] + o.y * attw[gl * 2 + 1];
      #pragma unroll
      for (int msk = 1; msk < 64; msk <<= 1) s += __shfl_xor(s, msk);
      if (gl == 0) logv[d] = s + attb[0];
    }
  }
}

// ---------------------------------------------------------------- global softmax
__global__ void __launch_bounds__(1024) k_stats(const float* logc, const float* logm, float* stats) {
  const float* src = (blockIdx.x == 0) ? logc : logm;
  int n = (blockIdx.x == 0) ? NC : NM;
  float m = -1e30f;
  for (int i = threadIdx.x; i < n; i += 1024) m = fmaxf(m, src[i]);
  __shared__ float sd[1024];
  sd[threadIdx.x] = m; __syncthreads();
  for (int off = 512; off > 0; off >>= 1) {
    if ((int)threadIdx.x < off) sd[threadIdx.x] = fmaxf(sd[threadIdx.x], sd[threadIdx.x + off]);
    __syncthreads();
  }
  if (threadIdx.x == 0) stats[blockIdx.x] = sd[0];
}

__global__ void __launch_bounds__(256) k_expsum(float* logc, float* logm, float* stats) {
  bool card = (int)blockIdx.x < 256;
  float* logv = card ? logc : logm;
  int n = card ? NC : NM;
  float mx = card ? stats[0] : stats[1];
  int b0 = card ? (int)blockIdx.x : (int)blockIdx.x - 256;
  int nb = card ? 256 : 64;
  float local = 0.f;
  for (int i = b0 * 256 + (int)threadIdx.x; i < n; i += nb * 256) {
    float e = __expf(logv[i] - mx);
    logv[i] = e;        // store numerator for later
    local += e;
  }
  __shared__ float sd[256];
  sd[threadIdx.x] = local; __syncthreads();
  for (int off = 128; off > 0; off >>= 1) {
    if ((int)threadIdx.x < off) sd[threadIdx.x] += sd[threadIdx.x + off];
    __syncthreads();
  }
  if (threadIdx.x == 0) atomicAdd(card ? &stats[2] : &stats[3], sd[0]);
}

// ---------------------------------------------------------------- launch
extern "C" void kernel_launch(void* const* d_in, const int* in_sizes, int n_in,
                              void* d_out, int out_size, void* d_ws, size_t ws_size,
                              hipStream_t stream) {
  (void)in_sizes; (void)n_in; (void)out_size; (void)ws_size;
  const float* x_card    = (const float*)d_in[0];
  const float* x_mer     = (const float*)d_in[1];
  const float* l0cm_Wsrc = (const float*)d_in[2];
  const float* l0cm_Wdst = (const float*)d_in[3];
  const float* l0cm_asrc = (const float*)d_in[4];
  const float* l0cm_adst = (const float*)d_in[5];
  const float* l0cm_b    = (const float*)d_in[6];
  const float* l0mc_Wsrc = (const float*)d_in[7];
  const float* l0mc_Wdst = (const float*)d_in[8];
  const float* l0mc_asrc = (const float*)d_in[9];
  const float* l0mc_adst = (const float*)d_in[10];
  const float* l0mc_b    = (const float*)d_in[11];
  const float* l1cm_Wsrc = (const float*)d_in[12];
  const float* l1cm_Wdst = (const float*)d_in[13];
  const float* l1cm_asrc = (const float*)d_in[14];
  const float* l1cm_adst = (const float*)d_in[15];
  const float* l1cm_b    = (const float*)d_in[16];
  const float* l1mc_Wsrc = (const float*)d_in[17];
  const float* l1mc_Wdst = (const float*)d_in[18];
  const float* l1mc_asrc = (const float*)d_in[19];
  const float* l1mc_adst = (const float*)d_in[20];
  const float* l1mc_b    = (const float*)d_in[21];
  const float* attw_c    = (const float*)d_in[22];
  const float* attb_c    = (const float*)d_in[23];
  const float* attw_m    = (const float*)d_in[24];
  const float* attb_m    = (const float*)d_in[25];
  const float* clsc_W1   = (const float*)d_in[26];
  const float* clsc_b1   = (const float*)d_in[27];
  const float* clsc_W2   = (const float*)d_in[28];
  const float* clsc_b2   = (const float*)d_in[29];
  const float* clsm_W1   = (const float*)d_in[30];
  const float* clsm_b1   = (const float*)d_in[31];
  const float* clsm_W2   = (const float*)d_in[32];
  const float* clsm_b2   = (const float*)d_in[33];
  const float* risk_W1   = (const float*)d_in[34];
  const float* risk_b1   = (const float*)d_in[35];
  const float* risk_W2   = (const float*)d_in[36];
  const float* risk_b2   = (const float*)d_in[37];
  const int*   cm_src    = (const int*)d_in[38];
  const int*   cm_dst    = (const int*)d_in[39];
  const int*   mc_src    = (const int*)d_in[40];
  const int*   mc_dst    = (const int*)d_in[41];
  float* out = (float*)d_out;

  float* base = (float*)d_ws;
  size_t o = 0;
  auto alloc = [&](size_t n) { float* p = base + o; o += (n + 3) & ~size_t(3); return p; };
  float* hs_card = alloc((size_t)NC * 128);   // f16 hs for cards (both layers)
  float* xc1     = alloc((size_t)NC * 128);   // xc1, then xc2raw
  float* hs_mer  = alloc((size_t)NM * 128);
  float* xm1     = alloc((size_t)NM * 128);
  float* as_card = alloc((size_t)NC * 4);
  float* ad_card = alloc((size_t)NC * 4);
  float* as_mer  = alloc((size_t)NM * 4);
  float* ad_mer  = alloc((size_t)NM * 4);
  float* v_l0cm  = alloc(512);
  float* v_l0mc  = alloc(512);
  float* v_l1cm  = alloc(512);
  float* v_l1mc  = alloc(512);
  float* bC      = alloc(128);
  float* bM      = alloc(128);
  f16* Bf_l0cm = (f16*)alloc(64 * 128 / 2);
  f16* Bf_l0mc = (f16*)alloc(64 * 128 / 2);
  f16* Bf_l1cm = (f16*)alloc(128 * 128 / 2);
  f16* Bf_l1mc = (f16*)alloc(128 * 128 / 2);
  f16* Bf_catC = (f16*)alloc(128 * 128 / 2);
  f16* Bf_catM = (f16*)alloc(128 * 128 / 2);
  float* logc    = alloc(NC);
  float* logm    = alloc(NM);
  float* stats   = alloc(4);                  // [maxc, maxm, denc, denm]
  int* cnt_cm  = (int*)alloc(NM);
  int* cnt_mc  = (int*)alloc(NC);
  int* offs_cm = (int*)alloc(NM + 1);
  int* offs_mc = (int*)alloc(NC + 1);
  int* cur_cm  = (int*)alloc(NM);
  int* cur_mc  = (int*)alloc(NC);
  int* parts   = (int*)alloc(128);
  int* csr_cm  = (int*)alloc(NE);
  int* csr_mc  = (int*)alloc(NE);

  const dim3 B256(256);
  k_prep<<<dim3(277), B256, 0, stream>>>(
      cnt_cm, NM + NC, (int*)stats,
      l0cm_Wdst, l0cm_adst, v_l0cm, l0mc_Wdst, l0mc_adst, v_l0mc,
      l1cm_Wdst, l1cm_adst, v_l1cm, l1mc_Wdst, l1mc_adst, v_l1mc,
      clsc_b1, clsm_b1, risk_b1, bC, bM,
      l0cm_Wsrc, l0mc_Wsrc, l1cm_Wsrc, l1mc_Wsrc,
      clsc_W1, clsm_W1, risk_W1,
      Bf_l0cm, Bf_l0mc, Bf_l1cm, Bf_l1mc, Bf_catC, Bf_catM);
  k_hist<<<dim3(512), B256, 0, stream>>>(cm_dst, mc_dst, cnt_cm, cnt_mc);
  k_scan1<<<dim3(118), B256, 0, stream>>>(cnt_cm, cnt_mc, offs_cm, offs_mc, parts);
  k_scan2<<<dim3(2), B256, 0, stream>>>(parts);
  k_scan3<<<dim3(469), B256, 0, stream>>>(offs_cm, offs_mc, cur_cm, cur_mc, parts);
  k_scatter<<<dim3(512), B256, 0, stream>>>(cm_src, cm_dst, mc_src, mc_dst,
                                            cur_cm, cur_mc, csr_cm, csr_mc);
  const int gA = (NC + 63) / 64;   // 1563
  const int gB = (NM + 63) / 64;   // 313

  GemmSide sA, sB;
  // ---- layer 0
  sA = {x_card, Bf_l0cm, l0cm_asrc, v_l0mc, (f16*)hs_card, as_card, ad_card,
        nullptr, nullptr, nullptr, nullptr, nullptr, nullptr, nullptr, nullptr,
        nullptr, nullptr, NC};
  sB = {x_mer, Bf_l0mc, l0mc_asrc, v_l0cm, (f16*)hs_mer, as_mer, ad_mer,
        nullptr, nullptr, nullptr, nullptr, nullptr, nullptr, nullptr, nullptr,
        nullptr, nullptr, NM};
  k_gemm<64, 0><<<dim3(gA + gB), B256, 0, stream>>>(sA, sB, gA);
  k_agg<<<dim3(NM + NC), dim3(128), 0, stream>>>(
      offs_cm, csr_cm, as_card, ad_mer, (const f16*)hs_card, l0cm_b, xm1,
      nullptr, nullptr, nullptr, NM,
      offs_mc, csr_mc, as_mer, ad_card, (const f16*)hs_mer, l0mc_b, xc1,
      nullptr, nullptr, nullptr);
  // ---- layer 1
  sA = {xc1, Bf_l1cm, l1cm_asrc, v_l1mc, (f16*)hs_card, as_card, ad_card,
        nullptr, nullptr, nullptr, nullptr, nullptr, nullptr, nullptr, nullptr,
        nullptr, nullptr, NC};
  sB = {xm1, Bf_l1mc, l1mc_asrc, v_l1cm, (f16*)hs_mer, as_mer, ad_mer,
        nullptr, nullptr, nullptr, nullptr, nullptr, nullptr, nullptr, nullptr,
        nullptr, nullptr, NM};
  k_gemm<128, 0><<<dim3(gA + gB), B256, 0, stream>>>(sA, sB, gA);
  k_agg<<<dim3(NM + NC), dim3(128), 0, stream>>>(
      offs_cm, csr_cm, as_card, ad_mer, (const f16*)hs_card, l1cm_b, xm1,
      attw_m, attb_m, logm, NM,                                           // xm2raw + merchant logits
      offs_mc, csr_mc, as_mer, ad_card, (const f16*)hs_mer, l1mc_b, xc1,
      attw_c, attb_c, logc);                                              // xc2raw + card logits
  // ---- global node softmax stats
  k_stats<<<dim3(2), dim3(1024), 0, stream>>>(logc, logm, stats);
  k_expsum<<<dim3(320), B256, 0, stream>>>(logc, logm, stats);
  // ---- fused: xc2/xm2 outputs + MLP(hidden+heads) via MFMA
  sA = {xc1, Bf_catC, nullptr, nullptr, nullptr, nullptr, nullptr,
        bC, logc, stats + 2, out,
        clsc_W2, clsc_b2, risk_W2, risk_b2,
        out + OFF_PC, out + OFF_RC, NC};
  sB = {xm1, Bf_catM, nullptr, nullptr, nullptr, nullptr, nullptr,
        bM, logm, stats + 3, out + OFF_XM2,
        clsm_W2, clsm_b2, risk_W2, risk_b2,
        out + OFF_PM, out + OFF_RM, NM};
  k_gemm<128, 1><<<dim3(gA + gB), B256, 0, stream>>>(sA, sB, gA);
}

// Round 4
// 510.029 us; speedup vs baseline: 1.6564x; 1.1797x over previous
//
#include <hip/hip_runtime.h>

typedef _Float16 f16;
typedef _Float16 f16x2 __attribute__((ext_vector_type(2)));
typedef _Float16 f16x4 __attribute__((ext_vector_type(4)));
typedef _Float16 f16x8 __attribute__((ext_vector_type(8)));
typedef float floatx4 __attribute__((ext_vector_type(4)));

// Problem constants (fixed by the reference)
constexpr int NC = 100000;   // cards
constexpr int NM = 20000;    // merchants
constexpr int NE = 400000;   // edges per edge-type

// d_out layout (floats), concat of (xc2, xm2, pred_c, pred_m, risk_c, risk_m)
constexpr int OFF_XM2 = NC * 128;
constexpr int OFF_PC  = OFF_XM2 + NM * 128;
constexpr int OFF_PM  = OFF_PC + NC * 2;
constexpr int OFF_RC  = OFF_PM + NM * 2;
constexpr int OFF_RM  = OFF_RC + NC;

__device__ __forceinline__ int bpermi(int v, int srclane) {
  return __builtin_amdgcn_ds_bpermute(srclane << 2, v);
}
__device__ __forceinline__ float bpermf(float v, int srclane) {
  int r = __builtin_amdgcn_ds_bpermute(srclane << 2, __builtin_bit_cast(int, v));
  return __builtin_bit_cast(float, r);
}

// ---------------------------------------------------------------- fused prep
// blocks 0..255: zero counters+stats. block 256: a_d GEMV vectors + bias concat.
// blocks 257..276: swizzle W matrices into MFMA B-fragment fp16 order.
// B-frag layout (16x16x32): lane holds B[k=kt*32+(lane>>4)*8+j][n=ct*16+(lane&15)],
// flat: dst[((kt*8+ct)*64+lane)*8+j]
__global__ void __launch_bounds__(256) k_prep(
    int* zero_base, int nzero, int* stats_i,
    const float* W0, const float* a0, float* v0,
    const float* W1, const float* a1, float* v1,
    const float* W2, const float* a2, float* v2,
    const float* W3, const float* a3, float* v3,
    const float* cb1, const float* mb1, const float* rb1, float* bC, float* bM,
    const float* S0, const float* S1, const float* S2, const float* S3,
    const float* c1, const float* m1, const float* r1,
    f16* BfL0cm, f16* BfL0mc, f16* BfL1cm, f16* BfL1mc, f16* BfC, f16* BfM) {
  int b = blockIdx.x, t = threadIdx.x;
  if (b < 256) {
    for (int i = b * 256 + t; i < nzero + 4; i += 256 * 256) {
      if (i < nzero) zero_base[i] = 0; else stats_i[i - nzero] = 0;
    }
  } else if (b == 256) {
    const float* Wd[4] = {W0, W1, W2, W3};
    const float* ad[4] = {a0, a1, a2, a3};
    float* vd[4] = {v0, v1, v2, v3};
    for (int idx = t; idx < 1536; idx += 256) {
      int mat, base;
      if (idx < 256)       { mat = 0; base = 0; }
      else if (idx < 512)  { mat = 1; base = 256; }
      else if (idx < 1024) { mat = 2; base = 512; }
      else                 { mat = 3; base = 1024; }
      int local = idx - base, k = local >> 2, h = local & 3;
      const float* W = Wd[mat]; const float* a = ad[mat];
      float s = 0.f;
      for (int c = 0; c < 32; ++c) s += W[k * 128 + h * 32 + c] * a[h * 32 + c];
      vd[mat][local] = s;
    }
    if (t < 128) {
      bC[t] = (t < 64) ? cb1[t] : rb1[t - 64];
      bM[t] = (t < 64) ? mb1[t] : rb1[t - 64];
    }
  } else {
    int s = b - 257;
    const float* Wp = nullptr; const float* cA = nullptr; const float* cB = nullptr;
    f16* dst; int kt;
    if (s < 2)       { Wp = S0; dst = BfL0cm; kt = s; }
    else if (s < 4)  { Wp = S1; dst = BfL0mc; kt = s - 2; }
    else if (s < 8)  { Wp = S2; dst = BfL1cm; kt = s - 4; }
    else if (s < 12) { Wp = S3; dst = BfL1mc; kt = s - 8; }
    else if (s < 16) { cA = c1; cB = r1; dst = BfC; kt = s - 12; }
    else             { cA = m1; cB = r1; dst = BfM; kt = s - 16; }
    for (int e = t; e < 512; e += 256) {
      int lane = e & 63, ct = e >> 6;
      int m = lane & 15, q = lane >> 4;
      int col = ct * 16 + m;
      f16x8 frag;
      #pragma unroll
      for (int j = 0; j < 8; ++j) {
        int k = kt * 32 + q * 8 + j;
        float val = Wp ? Wp[k * 128 + col]
                       : (col < 64 ? cA[k * 64 + col] : cB[k * 64 + (col - 64)]);
        frag[j] = (f16)val;
      }
      *reinterpret_cast<f16x8*>(&dst[(size_t)((kt * 8 + ct) * 64 + lane) * 8]) = frag;
    }
  }
}

// ---------------------------------------------------------------- CSR build
__global__ void k_hist(const int* cm_dst, const int* mc_dst, int* cnt_cm, int* cnt_mc) {
  int i = blockIdx.x * blockDim.x + threadIdx.x;
  int stride = gridDim.x * blockDim.x;
  for (; i < NE; i += stride) {
    atomicAdd(&cnt_cm[cm_dst[i]], 1);
    atomicAdd(&cnt_mc[mc_dst[i]], 1);
  }
}

__global__ void __launch_bounds__(256) k_scan1(const int* cnt_cm, const int* cnt_mc,
                                               int* offs_cm, int* offs_mc, int* parts) {
  int b = blockIdx.x;
  const int* cnt; int* offs; int n, chunk;
  if (b < 20) { cnt = cnt_cm; offs = offs_cm; n = NM; chunk = b; }
  else        { cnt = cnt_mc; offs = offs_mc; n = NC; chunk = b - 20; }
  int t = threadIdx.x;
  int base = chunk * 1024;
  int v[4]; int tsum = 0;
  #pragma unroll
  for (int j = 0; j < 4; ++j) {
    int idx = base + t * 4 + j;
    v[j] = (idx < n) ? cnt[idx] : 0;
    tsum += v[j];
  }
  __shared__ int sd[256];
  sd[t] = tsum; __syncthreads();
  for (int off = 1; off < 256; off <<= 1) {
    int x = (t >= off) ? sd[t - off] : 0;
    __syncthreads();
    sd[t] += x;
    __syncthreads();
  }
  int excl = sd[t] - tsum;
  int r = excl;
  #pragma unroll
  for (int j = 0; j < 4; ++j) {
    int idx = base + t * 4 + j;
    if (idx < n) offs[idx] = r;
    r += v[j];
  }
  if (t == 0) parts[b] = sd[255];
}

__global__ void __launch_bounds__(256) k_scan2(int* parts) {
  int b = blockIdx.x;
  int base = (b == 0) ? 0 : 20;
  int n = (b == 0) ? 20 : 98;
  int t = threadIdx.x;
  __shared__ int sd[128];
  int v = 0;
  if (t < 128) { v = (t < n) ? parts[base + t] : 0; sd[t] = v; }
  __syncthreads();
  for (int off = 1; off < 128; off <<= 1) {
    int x = 0;
    if (t < 128 && t >= off) x = sd[t - off];
    __syncthreads();
    if (t < 128) sd[t] += x;
    __syncthreads();
  }
  if (t < 128 && t < n) parts[base + t] = sd[t] - v;
}

__global__ void k_scan3(int* offs_cm, int* offs_mc, int* cur_cm, int* cur_mc, const int* parts) {
  int i = blockIdx.x * blockDim.x + threadIdx.x;
  if (i < NM) {
    int val = offs_cm[i] + parts[i >> 10];
    offs_cm[i] = val; cur_cm[i] = val;
  } else if (i < NM + NC) {
    int j = i - NM;
    int val = offs_mc[j] + parts[20 + (j >> 10)];
    offs_mc[j] = val; cur_mc[j] = val;
  }
  if (i == 0) { offs_cm[NM] = NE; offs_mc[NC] = NE; }
}

__global__ void k_scatter(const int* cm_src, const int* cm_dst,
                          const int* mc_src, const int* mc_dst,
                          int* cur_cm, int* cur_mc, int* csr_cm, int* csr_mc) {
  int i = blockIdx.x * blockDim.x + threadIdx.x;
  int stride = gridDim.x * blockDim.x;
  for (; i < NE; i += stride) {
    int p = atomicAdd(&cur_cm[cm_dst[i]], 1);
    csr_cm[p] = cm_src[i];
    int q = atomicAdd(&cur_mc[mc_dst[i]], 1);
    csr_mc[q] = mc_src[i];
  }
}

// ---------------------------------------------------------------- MFMA GEMM
// 64-row x 128-col tile per 256-thread block; 4 waves, each: 16 rows x 128 cols
// via 8 col-tiles of mfma_f32_16x16x32_f16 over K/32 k-tiles.
// C/D layout: col = ct*16 + (lane&15), row = (lane>>4)*4 + reg
struct GemmSide {
  const float* x; const f16* Bf;
  const float* asrc; const float* v; f16* hs; float* asO; float* adO;   // EPI 0
  const float* bias; const float* wnum; const float* den; float* outx;  // EPI 1
  const float* W2; const float* B2; const float* w2r; const float* b2r;
  float* pred; float* risk;
  int M;
};

template<int K, int EPI>
__global__ void __launch_bounds__(256) k_gemm(GemmSide A, GemmSide B, int gridA) {
  constexpr int PP = K + 8;        // fp16 pitch
  constexpr int F4 = K / 4;
  __shared__ f16 xs16[64 * PP];
  const bool isA = (int)blockIdx.x < gridA;
  GemmSide S = isA ? A : B;
  const int blk = isA ? (int)blockIdx.x : (int)blockIdx.x - gridA;
  const int rows0 = blk * 64;
  const int t = (int)threadIdx.x;
  float invden_s = 0.f;
  if constexpr (EPI == 1) invden_s = 1.0f / S.den[0];
  const float4* x4 = reinterpret_cast<const float4*>(S.x);
  #pragma unroll
  for (int ii = 0; ii < (64 * F4) / 256; ++ii) {
    int idx = t + ii * 256;
    int r = idx / F4, f = idx % F4;
    int gr = rows0 + r;
    float4 val = {0.f, 0.f, 0.f, 0.f};
    if (gr < S.M) val = x4[(size_t)gr * F4 + f];
    f16x4 hv; hv.x = (f16)val.x; hv.y = (f16)val.y; hv.z = (f16)val.z; hv.w = (f16)val.w;
    *reinterpret_cast<f16x4*>(&xs16[r * PP + f * 4]) = hv;
    if constexpr (EPI == 1) {
      if (gr < S.M) {
        float w = S.wnum[gr] * invden_s;
        float4 ov = {val.x * w, val.y * w, val.z * w, val.w * w};
        *reinterpret_cast<float4*>(&S.outx[(size_t)gr * 128 + f * 4]) = ov;
      }
    }
  }
  __syncthreads();
  const int lane = t & 63, w = t >> 6;
  const int m = lane & 15, q = lane >> 4;
  const int rbase = w * 16;
  floatx4 acc[8];
  #pragma unroll
  for (int ct = 0; ct < 8; ++ct) acc[ct] = {0.f, 0.f, 0.f, 0.f};
  const f16x8* Bf8 = reinterpret_cast<const f16x8*>(S.Bf);
  #pragma unroll
  for (int kt = 0; kt < K / 32; ++kt) {
    f16x8 a = *reinterpret_cast<const f16x8*>(&xs16[(rbase + m) * PP + kt * 32 + q * 8]);
    #pragma unroll
    for (int ct = 0; ct < 8; ++ct) {
      f16x8 b = Bf8[(kt * 8 + ct) * 64 + lane];
      acc[ct] = __builtin_amdgcn_mfma_f32_16x16x32_f16(a, b, acc[ct], 0, 0, 0);
    }
  }
  if constexpr (EPI == 0) {
    // ---- hs f16 store: pair columns via xor-1 shuffle
    #pragma unroll
    for (int reg = 0; reg < 4; ++reg) {
      int gr = rows0 + rbase + q * 4 + reg;
      bool ok = gr < S.M;
      #pragma unroll
      for (int cp = 0; cp < 4; ++cp) {
        float v0 = acc[2 * cp][reg], v1 = acc[2 * cp + 1][reg];
        float w0 = __shfl_xor(v0, 1), w1 = __shfl_xor(v1, 1);
        bool even = (m & 1) == 0;
        f16x2 pr;
        pr.x = (f16)(even ? v0 : w1);
        pr.y = (f16)(even ? w0 : v1);
        int col = even ? (2 * cp) * 16 + m : (2 * cp + 1) * 16 + m - 1;
        if (ok) *reinterpret_cast<f16x2*>(&S.hs[(size_t)gr * 128 + col]) = pr;
      }
    }
    // ---- a_s
    float as0[4], as1[4];
    #pragma unroll
    for (int h = 0; h < 4; ++h) { as0[h] = S.asrc[h * 32 + m]; as1[h] = S.asrc[h * 32 + 16 + m]; }
    #pragma unroll
    for (int reg = 0; reg < 4; ++reg) {
      float p[4];
      #pragma unroll
      for (int h = 0; h < 4; ++h)
        p[h] = acc[2 * h][reg] * as0[h] + acc[2 * h + 1][reg] * as1[h];
      #pragma unroll
      for (int off = 1; off < 16; off <<= 1) {
        #pragma unroll
        for (int h = 0; h < 4; ++h) p[h] += __shfl_xor(p[h], off);
      }
      int gr = rows0 + rbase + q * 4 + reg;
      if (m == 0 && gr < S.M) {
        float4 pv = {p[0], p[1], p[2], p[3]};
        *reinterpret_cast<float4*>(&S.asO[gr * 4]) = pv;
      }
    }
    // ---- a_d: GEMV x @ v from LDS
    float qd[4] = {0.f, 0.f, 0.f, 0.f};
    const float4* v4p = reinterpret_cast<const float4*>(S.v);
    constexpr int KS = K / 4;
    #pragma unroll
    for (int i = 0; i < KS; ++i) {
      int k = q * KS + i;
      float xv = (float)xs16[(rbase + m) * PP + k];
      float4 vk = v4p[k];
      qd[0] += xv * vk.x; qd[1] += xv * vk.y; qd[2] += xv * vk.z; qd[3] += xv * vk.w;
    }
    #pragma unroll
    for (int h = 0; h < 4; ++h) {
      qd[h] += __shfl_xor(qd[h], 16);
      qd[h] += __shfl_xor(qd[h], 32);
    }
    int gr2 = rows0 + rbase + m;
    if (q == 0 && gr2 < S.M) {
      float4 qv = {qd[0], qd[1], qd[2], qd[3]};
      *reinterpret_cast<float4*>(&S.adO[gr2 * 4]) = qv;
    }
  } else {
    // ---- fused MLP-2 + heads
    float wn[4];
    #pragma unroll
    for (int reg = 0; reg < 4; ++reg) {
      int gr = rows0 + rbase + q * 4 + reg;
      wn[reg] = (gr < S.M) ? S.wnum[gr] * invden_s : 0.f;
    }
    float bct[8], w2c0[4], w2c1[4], w2rv[4];
    #pragma unroll
    for (int ct = 0; ct < 8; ++ct) bct[ct] = S.bias[ct * 16 + m];
    #pragma unroll
    for (int ct = 0; ct < 4; ++ct) {
      int col = ct * 16 + m;
      w2c0[ct] = S.W2[col * 2];
      w2c1[ct] = S.W2[col * 2 + 1];
      w2rv[ct] = S.w2r[col];
    }
    #pragma unroll
    for (int reg = 0; reg < 4; ++reg) {
      float p0 = 0.f, p1 = 0.f, rr = 0.f;
      #pragma unroll
      for (int ct = 0; ct < 4; ++ct) {
        float hv = fmaxf(acc[ct][reg] * wn[reg] + bct[ct], 0.f);
        p0 += hv * w2c0[ct];
        p1 += hv * w2c1[ct];
      }
      #pragma unroll
      for (int ct = 4; ct < 8; ++ct) {
        float hv = fmaxf(acc[ct][reg] * wn[reg] + bct[ct], 0.f);
        rr += hv * w2rv[ct - 4];
      }
      #pragma unroll
      for (int off = 1; off < 16; off <<= 1) {
        p0 += __shfl_xor(p0, off);
        p1 += __shfl_xor(p1, off);
        rr += __shfl_xor(rr, off);
      }
      int gr = rows0 + rbase + q * 4 + reg;
      if (m == 0 && gr < S.M) {
        float2 pp = {p0 + S.B2[0], p1 + S.B2[1]};
        *reinterpret_cast<float2*>(&S.pred[gr * 2]) = pp;
        float z = rr + S.b2r[0];
        S.risk[gr] = 1.f / (1.f + __expf(-z));
      }
    }
  }
}

// ---------------------------------------------------------------- aggregation
// ONE WAVE per destination node, 4 dst per 256-block. No LDS, no barriers.
// Weight role: lane = (edge&15)*4 + head computes e/exp once; per-head
// max/sum via shfl_xor strides 4..32. Cross-role broadcast via ds_bpermute.
// Gather role: lane = channel pair (2l, 2l+1), head gh = lane>>4; 4 loads
// in flight via hand-unrolled batches.
struct AggSide {
  const int* offs; const int* csr; const float* as_; const float* ad;
  const f16* hs; const float* bias; float* out;
  const float* attw; const float* attb; float* logv;
};

__global__ void __launch_bounds__(256) k_agg(AggSide A, AggSide B, int ndstA, int ntot) {
  const int wid = (int)blockIdx.x * 4 + ((int)threadIdx.x >> 6);
  if (wid >= ntot) return;
  const bool isA = wid < ndstA;
  const AggSide S = isA ? A : B;
  const int d = isA ? wid : wid - ndstA;
  const int lane = (int)threadIdx.x & 63;
  const int we = lane >> 2, wh = lane & 3;   // weight role: edge-in-chunk, head
  const int gh = lane >> 4;                  // gather role: head of channel pair
  const int beg = S.offs[d], end = S.offs[d + 1];
  const float adv = S.ad[d * 4 + wh];
  const f16* __restrict__ hsp = S.hs;
  float m_run = -1e30f, den = 0.f;
  float accx = 0.f, accy = 0.f;
  for (int base = beg; base < end; base += 16) {
    const int n = min(16, end - base);
    int s = 0; float e = -1e30f;
    if (we < n) {
      s = S.csr[base + we];
      float ev = S.as_[s * 4 + wh] + adv;
      e = (ev > 0.f) ? ev : 0.2f * ev;
    }
    float cm = e;
    #pragma unroll
    for (int msk = 4; msk < 64; msk <<= 1) cm = fmaxf(cm, __shfl_xor(cm, msk));
    const float m_new = fmaxf(m_run, cm);
    const float scale = __expf(m_run - m_new);   // 0 on first chunk
    const float w = __expf(e - m_new);           // 0 for invalid lanes
    float ws = w;
    #pragma unroll
    for (int msk = 4; msk < 64; msk <<= 1) ws += __shfl_xor(ws, msk);
    den = den * scale + ws;
    m_run = m_new;
    const float sg = bpermf(scale, gh);
    accx *= sg; accy *= sg;
    int j = 0;
    for (; j + 4 <= n; j += 4) {
      int s0 = bpermi(s, (j + 0) * 4);
      int s1 = bpermi(s, (j + 1) * 4);
      int s2 = bpermi(s, (j + 2) * 4);
      int s3 = bpermi(s, (j + 3) * 4);
      float w0 = bpermf(w, (j + 0) * 4 + gh);
      float w1 = bpermf(w, (j + 1) * 4 + gh);
      float w2 = bpermf(w, (j + 2) * 4 + gh);
      float w3 = bpermf(w, (j + 3) * 4 + gh);
      f16x2 h0 = *reinterpret_cast<const f16x2*>(&hsp[s0 * 128 + lane * 2]);
      f16x2 h1 = *reinterpret_cast<const f16x2*>(&hsp[s1 * 128 + lane * 2]);
      f16x2 h2 = *reinterpret_cast<const f16x2*>(&hsp[s2 * 128 + lane * 2]);
      f16x2 h3 = *reinterpret_cast<const f16x2*>(&hsp[s3 * 128 + lane * 2]);
      accx += w0 * (float)h0.x + w1 * (float)h1.x + w2 * (float)h2.x + w3 * (float)h3.x;
      accy += w0 * (float)h0.y + w1 * (float)h1.y + w2 * (float)h2.y + w3 * (float)h3.y;
    }
    for (; j < n; ++j) {
      int sj = bpermi(s, j * 4);
      float wj = bpermf(w, j * 4 + gh);
      f16x2 hj = *reinterpret_cast<const f16x2*>(&hsp[sj * 128 + lane * 2]);
      accx += wj * (float)hj.x;
      accy += wj * (float)hj.y;
    }
  }
  const float deng = bpermf(den, gh);
  const float invden = (deng > 0.f) ? 1.f / deng : 0.f;
  const float2 b2 = *reinterpret_cast<const float2*>(&S.bias[lane * 2]);
  float ox = accx * invden + b2.x;
  float oy = accy * invden + b2.y;
  float2 o = {ox, oy};
  *reinterpret_cast<float2*>(&S.out[d * 128 + lane * 2]) = o;
  if (S.attw) {
    float sl = ox * S.attw[lane * 2] + oy * S.attw[lane * 2 + 1];
    #pragma unroll
    for (int msk = 1; msk < 64; msk <<= 1) sl += __shfl_xor(sl, msk);
    if (lane == 0) S.logv[d] = sl + S.attb[0];
  }
}

// ---------------------------------------------------------------- global softmax
__global__ void __launch_bounds__(1024) k_stats(const float* logc, const float* logm, float* stats) {
  const float* src = (blockIdx.x == 0) ? logc : logm;
  int n = (blockIdx.x == 0) ? NC : NM;
  float m = -1e30f;
  for (int i = threadIdx.x; i < n; i += 1024) m = fmaxf(m, src[i]);
  __shared__ float sd[1024];
  sd[threadIdx.x] = m; __syncthreads();
  for (int off = 512; off > 0; off >>= 1) {
    if ((int)threadIdx.x < off) sd[threadIdx.x] = fmaxf(sd[threadIdx.x], sd[threadIdx.x + off]);
    __syncthreads();
  }
  if (threadIdx.x == 0) stats[blockIdx.x] = sd[0];
}

__global__ void __launch_bounds__(256) k_expsum(float* logc, float* logm, float* stats) {
  bool card = (int)blockIdx.x < 256;
  float* logv = card ? logc : logm;
  int n = card ? NC : NM;
  float mx = card ? stats[0] : stats[1];
  int b0 = card ? (int)blockIdx.x : (int)blockIdx.x - 256;
  int nb = card ? 256 : 64;
  float local = 0.f;
  for (int i = b0 * 256 + (int)threadIdx.x; i < n; i += nb * 256) {
    float e = __expf(logv[i] - mx);
    logv[i] = e;        // store numerator for later
    local += e;
  }
  __shared__ float sd[256];
  sd[threadIdx.x] = local; __syncthreads();
  for (int off = 128; off > 0; off >>= 1) {
    if ((int)threadIdx.x < off) sd[threadIdx.x] += sd[threadIdx.x + off];
    __syncthreads();
  }
  if (threadIdx.x == 0) atomicAdd(card ? &stats[2] : &stats[3], sd[0]);
}

// ---------------------------------------------------------------- launch
extern "C" void kernel_launch(void* const* d_in, const int* in_sizes, int n_in,
                              void* d_out, int out_size, void* d_ws, size_t ws_size,
                              hipStream_t stream) {
  (void)in_sizes; (void)n_in; (void)out_size; (void)ws_size;
  const float* x_card    = (const float*)d_in[0];
  const float* x_mer     = (const float*)d_in[1];
  const float* l0cm_Wsrc = (const float*)d_in[2];
  const float* l0cm_Wdst = (const float*)d_in[3];
  const float* l0cm_asrc = (const float*)d_in[4];
  const float* l0cm_adst = (const float*)d_in[5];
  const float* l0cm_b    = (const float*)d_in[6];
  const float* l0mc_Wsrc = (const float*)d_in[7];
  const float* l0mc_Wdst = (const float*)d_in[8];
  const float* l0mc_asrc = (const float*)d_in[9];
  const float* l0mc_adst = (const float*)d_in[10];
  const float* l0mc_b    = (const float*)d_in[11];
  const float* l1cm_Wsrc = (const float*)d_in[12];
  const float* l1cm_Wdst = (const float*)d_in[13];
  const float* l1cm_asrc = (const float*)d_in[14];
  const float* l1cm_adst = (const float*)d_in[15];
  const float* l1cm_b    = (const float*)d_in[16];
  const float* l1mc_Wsrc = (const float*)d_in[17];
  const float* l1mc_Wdst = (const float*)d_in[18];
  const float* l1mc_asrc = (const float*)d_in[19];
  const float* l1mc_adst = (const float*)d_in[20];
  const float* l1mc_b    = (const float*)d_in[21];
  const float* attw_c    = (const float*)d_in[22];
  const float* attb_c    = (const float*)d_in[23];
  const float* attw_m    = (const float*)d_in[24];
  const float* attb_m    = (const float*)d_in[25];
  const float* clsc_W1   = (const float*)d_in[26];
  const float* clsc_b1   = (const float*)d_in[27];
  const float* clsc_W2   = (const float*)d_in[28];
  const float* clsc_b2   = (const float*)d_in[29];
  const float* clsm_W1   = (const float*)d_in[30];
  const float* clsm_b1   = (const float*)d_in[31];
  const float* clsm_W2   = (const float*)d_in[32];
  const float* clsm_b2   = (const float*)d_in[33];
  const float* risk_W1   = (const float*)d_in[34];
  const float* risk_b1   = (const float*)d_in[35];
  const float* risk_W2   = (const float*)d_in[36];
  const float* risk_b2   = (const float*)d_in[37];
  const int*   cm_src    = (const int*)d_in[38];
  const int*   cm_dst    = (const int*)d_in[39];
  const int*   mc_src    = (const int*)d_in[40];
  const int*   mc_dst    = (const int*)d_in[41];
  float* out = (float*)d_out;

  float* base = (float*)d_ws;
  size_t o = 0;
  auto alloc = [&](size_t n) { float* p = base + o; o += (n + 3) & ~size_t(3); return p; };
  float* hs_card = alloc((size_t)NC * 128);   // f16 hs for cards (both layers)
  float* xc1     = alloc((size_t)NC * 128);   // xc1, then xc2raw
  float* hs_mer  = alloc((size_t)NM * 128);
  float* xm1     = alloc((size_t)NM * 128);
  float* as_card = alloc((size_t)NC * 4);
  float* ad_card = alloc((size_t)NC * 4);
  float* as_mer  = alloc((size_t)NM * 4);
  float* ad_mer  = alloc((size_t)NM * 4);
  float* v_l0cm  = alloc(512);
  float* v_l0mc  = alloc(512);
  float* v_l1cm  = alloc(512);
  float* v_l1mc  = alloc(512);
  float* bC      = alloc(128);
  float* bM      = alloc(128);
  f16* Bf_l0cm = (f16*)alloc(64 * 128 / 2);
  f16* Bf_l0mc = (f16*)alloc(64 * 128 / 2);
  f16* Bf_l1cm = (f16*)alloc(128 * 128 / 2);
  f16* Bf_l1mc = (f16*)alloc(128 * 128 / 2);
  f16* Bf_catC = (f16*)alloc(128 * 128 / 2);
  f16* Bf_catM = (f16*)alloc(128 * 128 / 2);
  float* logc    = alloc(NC);
  float* logm    = alloc(NM);
  float* stats   = alloc(4);                  // [maxc, maxm, denc, denm]
  int* cnt_cm  = (int*)alloc(NM);
  int* cnt_mc  = (int*)alloc(NC);
  int* offs_cm = (int*)alloc(NM + 1);
  int* offs_mc = (int*)alloc(NC + 1);
  int* cur_cm  = (int*)alloc(NM);
  int* cur_mc  = (int*)alloc(NC);
  int* parts   = (int*)alloc(128);
  int* csr_cm  = (int*)alloc(NE);
  int* csr_mc  = (int*)alloc(NE);

  const dim3 B256(256);
  k_prep<<<dim3(277), B256, 0, stream>>>(
      cnt_cm, NM + NC, (int*)stats,
      l0cm_Wdst, l0cm_adst, v_l0cm, l0mc_Wdst, l0mc_adst, v_l0mc,
      l1cm_Wdst, l1cm_adst, v_l1cm, l1mc_Wdst, l1mc_adst, v_l1mc,
      clsc_b1, clsm_b1, risk_b1, bC, bM,
      l0cm_Wsrc, l0mc_Wsrc, l1cm_Wsrc, l1mc_Wsrc,
      clsc_W1, clsm_W1, risk_W1,
      Bf_l0cm, Bf_l0mc, Bf_l1cm, Bf_l1mc, Bf_catC, Bf_catM);
  k_hist<<<dim3(512), B256, 0, stream>>>(cm_dst, mc_dst, cnt_cm, cnt_mc);
  k_scan1<<<dim3(118), B256, 0, stream>>>(cnt_cm, cnt_mc, offs_cm, offs_mc, parts);
  k_scan2<<<dim3(2), B256, 0, stream>>>(parts);
  k_scan3<<<dim3(469), B256, 0, stream>>>(offs_cm, offs_mc, cur_cm, cur_mc, parts);
  k_scatter<<<dim3(512), B256, 0, stream>>>(cm_src, cm_dst, mc_src, mc_dst,
                                            cur_cm, cur_mc, csr_cm, csr_mc);
  const int gA = (NC + 63) / 64;   // 1563
  const int gB = (NM + 63) / 64;   // 313
  const int NTOT = NM + NC;        // 120000
  const int gAgg = (NTOT + 3) / 4; // 30000

  GemmSide sA, sB;
  AggSide aA, aB;
  // ---- layer 0
  sA = {x_card, Bf_l0cm, l0cm_asrc, v_l0mc, (f16*)hs_card, as_card, ad_card,
        nullptr, nullptr, nullptr, nullptr, nullptr, nullptr, nullptr, nullptr,
        nullptr, nullptr, NC};
  sB = {x_mer, Bf_l0mc, l0mc_asrc, v_l0cm, (f16*)hs_mer, as_mer, ad_mer,
        nullptr, nullptr, nullptr, nullptr, nullptr, nullptr, nullptr, nullptr,
        nullptr, nullptr, NM};
  k_gemm<64, 0><<<dim3(gA + gB), B256, 0, stream>>>(sA, sB, gA);
  aA = {offs_cm, csr_cm, as_card, ad_mer, (const f16*)hs_card, l0cm_b, xm1,
        nullptr, nullptr, nullptr};
  aB = {offs_mc, csr_mc, as_mer, ad_card, (const f16*)hs_mer, l0mc_b, xc1,
        nullptr, nullptr, nullptr};
  k_agg<<<dim3(gAgg), B256, 0, stream>>>(aA, aB, NM, NTOT);
  // ---- layer 1
  sA = {xc1, Bf_l1cm, l1cm_asrc, v_l1mc, (f16*)hs_card, as_card, ad_card,
        nullptr, nullptr, nullptr, nullptr, nullptr, nullptr, nullptr, nullptr,
        nullptr, nullptr, NC};
  sB = {xm1, Bf_l1mc, l1mc_asrc, v_l1cm, (f16*)hs_mer, as_mer, ad_mer,
        nullptr, nullptr, nullptr, nullptr, nullptr, nullptr, nullptr, nullptr,
        nullptr, nullptr, NM};
  k_gemm<128, 0><<<dim3(gA + gB), B256, 0, stream>>>(sA, sB, gA);
  aA = {offs_cm, csr_cm, as_card, ad_mer, (const f16*)hs_card, l1cm_b, xm1,
        attw_m, attb_m, logm};
  aB = {offs_mc, csr_mc, as_mer, ad_card, (const f16*)hs_mer, l1mc_b, xc1,
        attw_c, attb_c, logc};
  k_agg<<<dim3(gAgg), B256, 0, stream>>>(aA, aB, NM, NTOT);
  // ---- global node softmax stats
  k_stats<<<dim3(2), dim3(1024), 0, stream>>>(logc, logm, stats);
  k_expsum<<<dim3(320), B256, 0, stream>>>(logc, logm, stats);
  // ---- fused: xc2/xm2 outputs + MLP(hidden+heads) via MFMA
  sA = {xc1, Bf_catC, nullptr, nullptr, nullptr, nullptr, nullptr,
        bC, logc, stats + 2, out,
        clsc_W2, clsc_b2, risk_W2, risk_b2,
        out + OFF_PC, out + OFF_RC, NC};
  sB = {xm1, Bf_catM, nullptr, nullptr, nullptr, nullptr, nullptr,
        bM, logm, stats + 3, out + OFF_XM2,
        clsm_W2, clsm_b2, risk_W2, risk_b2,
        out + OFF_PM, out + OFF_RM, NM};
  k_gemm<128, 1><<<dim3(gA + gB), B256, 0, stream>>>(sA, sB, gA);
}